// Round 6
// baseline (1419.622 us; speedup 1.0000x reference)
//
#include <hip/hip_runtime.h>
#include <stdint.h>
#include <algorithm>

// Sparse conv encoder on MI355X. R11: persistent mega-kernel.
// R10 analysis: depth-2 prefetch null (A-latency already covered at depth-1);
// remaining certain overhead = 8 inter-dispatch gaps (5.1us each measured
// R2->R3) + 8 kernel tail drains. R11 fuses everything into 2 dispatches:
// tiny init (barrier counters + zero page) + one persistent kernel.
// Grid-wide sync: monotonic atomic barrier, __threadfence release/acquire
// (device scope -> cross-XCD L2 wb/inv), __syncthreads drains block stores
// before arrival. Co-residency GUARANTEED: 512 blocks x 512 thr, LDS 80KB ->
// 2 blocks/CU, __launch_bounds__(512,4) caps VGPR at 128. Spin cap avoids
// hangs. mconv body is verbatim R10 (487us-proven: BK=64, A 3buf depth-2 /
// B 2buf depth-1, counted vmcnt(4), source-side XOR swizzle, zero-page fold,
// setprio) wrapped in a balanced bijective XCD-clustered tile loop.
// Predict: 491 -> ~430-455us; mega_kernel top dispatch ~380-420us,
// LDS 81920, VGPR <=128.

#define DI __device__ __forceinline__

typedef __attribute__((ext_vector_type(8))) short bf16x8;
typedef __attribute__((ext_vector_type(4))) float f32x4;

DI uint16_t f2bf(float x){
  union{float f;uint32_t i;}v; v.f=x;
  uint32_t r = v.i + 0x7fffu + ((v.i>>16)&1u);
  return (uint16_t)(r>>16);
}
DI uint32_t pack2(float a, float b){
  return (uint32_t)f2bf(a) | ((uint32_t)f2bf(b) << 16);
}
DI void gload16(const void* g, void* l){
  __builtin_amdgcn_global_load_lds(
      (const __attribute__((address_space(1))) void*)g,
      (__attribute__((address_space(3))) void*)l, 16, 0, 0);
}

__global__ __launch_bounds__(256) void diag_kernel(float* __restrict__ out, long n, float c){
  long i = (long)blockIdx.x*256 + threadIdx.x;
  if (i < n) out[i] = c;
}

// zero barrier counters + 256B zero page (must precede mega_kernel)
__global__ __launch_bounds__(256) void init_bar_kernel(int* __restrict__ bar,
                                                       float* __restrict__ zp){
  int t = threadIdx.x;
  if (t < 64) bar[t] = 0;
  if (t >= 64 && t < 128) zp[t-64] = 0.f;
}

struct MegaArgs {
  const char* wsb;
  int* tb;
  int* bar;
  long ntab;
  const int* im[6]; const int* om[6];
  int   M[6]; int nin[6]; int nout[6];
  long  toff[6];
  const float* w[5];           // prep_w sources (d0,c1,d1,c2,d2)
  long wtotal;
  uint16_t* wb;
  const float* feats; const float* w_c0; const float* b_c0;
  uint16_t* fbuf;
  int n0, n1, n2, n3;
  long wtb_off, zp_off, bf0_off, bf1_off;
  const float *b_d0, *b_c1, *b_d1, *b_c2, *b_d2;
  float *out0, *out1, *out2;
  uint16_t *bf0, *bf1;
};

// device-scope grid barrier: monotonic counter, target = phase*gridDim.
DI void gsync(int* bar, int target){
  __syncthreads();                    // block stores drained (vmcnt) & all arrived
  if (threadIdx.x == 0){
    __threadfence();                  // release: L2 writeback, device scope
    atomicAdd(bar, 1);
    int spins = 0;
    while (atomicAdd(bar, 0) < target){
      __builtin_amdgcn_s_sleep(8);
      if (++spins > 100000000) break; // safety: fail loud, never hang
    }
    __threadfence();                  // acquire: invalidate stale L1/L2
  }
  __syncthreads();
}

// Flattened-K gathered GEMM phase, verbatim R10 pipeline inside a tile loop.
// BM=128 x BN=128, BK=64, 8 waves (4x2), A 3buf depth-2, B 2buf depth-1.
template<int CIN, int OUTMODE, bool RELU>
DI void mconv_phase(uint8_t* smem, const char* ws_base, long in_off,
                    long wtb_off, long zp_off,
                    const float* __restrict__ bias, const int* __restrict__ tab,
                    float* __restrict__ outf, uint16_t* __restrict__ outb,
                    int n_out, int bid, int nblk){
  constexpr int NS = 9*CIN/64;
  uint16_t (*ab)[128*64] = (uint16_t(*)[128*64])smem;              // 3 x 16KB
  uint16_t (*bb)[128*64] = (uint16_t(*)[128*64])(smem + 3*16384);  // 2 x 16KB
  const int tid = threadIdx.x;

  // balanced bijective XCD-clustered tile split: adjacent tiles -> same XCD
  const int T = (n_out + 127) >> 7;
  const int q = T / nblk, r = T % nblk;
  const int sb = (bid & 7)*(nblk >> 3) + (bid >> 3);
  const int t0 = (sb < r) ? sb*(q+1) : r*(q+1) + (sb - r)*q;
  const int t1 = t0 + ((sb < r) ? (q+1) : q);

  const int r0 = tid >> 3, sg = tid & 7;
  const int ss0 = sg ^ (r0 & 7);
  const uint32_t offB = (uint32_t)(wtb_off + ((long)r0*CIN + ss0*8)*2);

  const int lane = tid & 63, wv = tid >> 6;
  const int wr = (wv >> 1) << 5;    // 4 row-waves x 32
  const int wc = (wv & 1) << 6;     // 2 col-waves x 64
  const int l16 = lane & 15, quad = lane >> 4;

  float bv[4];
  #pragma unroll
  for (int ct = 0; ct < 4; ++ct) bv[ct] = bias[wc + (ct<<4) + l16];

  for (int tile = t0; tile < t1; ++tile){
    __builtin_amdgcn_s_barrier();   // protect LDS from prior-tile stragglers
    const long rb = (long)tile * 128;

    uint32_t offA[2][9];
    #pragma unroll
    for (int kk = 0; kk < 9; ++kk){
      #pragma unroll
      for (int it = 0; it < 2; ++it){
        long row = rb + it*64 + r0;
        int gi = (row < (long)n_out) ? tab[(long)kk*n_out + row] : -1;
        offA[it][kk] = (gi >= 0)
            ? (uint32_t)(in_off + (long)gi*(CIN*2) + ss0*16)
            : (uint32_t)(zp_off + ss0*16);
      }
    }

    f32x4 acc[2][4];
    #pragma unroll
    for (int i = 0; i < 2; i++)
      #pragma unroll
      for (int j = 0; j < 4; j++)
        acc[i][j] = (f32x4){0.f,0.f,0.f,0.f};

    auto stage_a = [&](int step, int nb){
      const int kk  = (CIN == 64) ? step : (step >> 1);
      const int c0b = (CIN == 64) ? 0 : ((step & 1) * 128);
      #pragma unroll
      for (int it = 0; it < 2; ++it)
        gload16(ws_base + offA[it][kk] + c0b, &ab[nb][(it*512+tid)*8]);
    };
    auto stage_b = [&](int step, int nb){
      const int kk  = (CIN == 64) ? step : (step >> 1);
      const int c0b = (CIN == 64) ? 0 : ((step & 1) * 128);
      const uint32_t base = offB + (uint32_t)((long)kk*128*CIN*2 + c0b);
      #pragma unroll
      for (int it = 0; it < 2; ++it)
        gload16(ws_base + base + it*(64*CIN*2), &bb[nb][(it*512+tid)*8]);
    };
    auto compute = [&](int na, int nb){
      const uint16_t* A  = &ab[na][0];
      const uint16_t* Bm = &bb[nb][0];
      __builtin_amdgcn_s_setprio(1);
      #pragma unroll
      for (int ch = 0; ch < 2; ++ch){
        const int xs = ((((ch << 2) + quad) ^ (l16 & 7)) << 3);
        bf16x8 af[2], bfr[4];
        #pragma unroll
        for (int u = 0; u < 2; ++u)
          af[u]  = *(const bf16x8*)&A [((wr + (u<<4) + l16) << 6) + xs];
        #pragma unroll
        for (int u = 0; u < 4; ++u)
          bfr[u] = *(const bf16x8*)&Bm[((wc + (u<<4) + l16) << 6) + xs];
        #pragma unroll
        for (int rt = 0; rt < 2; ++rt)
          #pragma unroll
          for (int ct = 0; ct < 4; ++ct)
            acc[rt][ct] = __builtin_amdgcn_mfma_f32_16x16x32_bf16(
                af[rt], bfr[ct], acc[rt][ct], 0, 0, 0);
      }
      __builtin_amdgcn_s_setprio(0);
    };

    stage_a(0, 0);
    stage_a(1, 1);
    stage_b(0, 0);
    #pragma unroll
    for (int t = 0; t < NS; ++t){
      if (t + 2 < NS) stage_a(t+2, (t+2)%3);
      if (t + 1 < NS) stage_b(t+1, (t+1)&1);
      if (t + 2 < NS){
        asm volatile("s_waitcnt vmcnt(4)" ::: "memory");
      } else if (t + 1 < NS){
        asm volatile("s_waitcnt vmcnt(2)" ::: "memory");
      } else {
        asm volatile("s_waitcnt vmcnt(0)" ::: "memory");
      }
      __builtin_amdgcn_sched_barrier(0);
      __builtin_amdgcn_s_barrier();
      compute(t%3, t&1);
      if (t + 1 < NS)
        __builtin_amdgcn_s_barrier();
    }

    #pragma unroll
    for (int ct = 0; ct < 4; ++ct){
      const int cout = wc + (ct<<4) + l16;
      #pragma unroll
      for (int rt = 0; rt < 2; ++rt){
        #pragma unroll
        for (int rr2 = 0; rr2 < 4; ++rr2){
          long row = rb + wr + (rt<<4) + (quad<<2) + rr2;
          if (row < (long)n_out){
            float v = acc[rt][ct][rr2] + bv[ct];
            if (RELU) v = v > 0.f ? v : 0.f;
            if constexpr (OUTMODE == 0 || OUTMODE == 2) outf[row*128 + cout] = v;
            if constexpr (OUTMODE == 1 || OUTMODE == 2) outb[row*128 + cout] = f2bf(v);
          }
        }
      }
    }
  }
}

__global__ __launch_bounds__(512,4) void mega_kernel(MegaArgs a){
  __shared__ __align__(16) uint8_t smem[81920];
  const int tid = threadIdx.x, bid = blockIdx.x;
  const int nblk = gridDim.x;
  const long gid = (long)bid*512 + tid;
  const long gstride = (long)nblk*512;

  // ph0: tables = -1, weight transposes (zero page done by init_bar_kernel)
  for (long i = gid; i < a.ntab; i += gstride) a.tb[i] = -1;
  {
    const long wt64 = 9L*128*64, wt128 = 9L*128*128;
    for (long idx = gid; idx < a.wtotal; idx += gstride){
      int L; long rr; int cin;
      if (idx < wt64){ L = 0; rr = idx; cin = 64; }
      else { long j = idx - wt64; L = 1 + (int)(j / wt128); rr = j % wt128; cin = 128; }
      const float* w = a.w[L];
      int k = (int)(rr / (128*cin));
      int rem = (int)(rr % (128*cin));
      int cout = rem / cin, ci = rem % cin;
      a.wb[idx] = f2bf(w[((long)k*cin + ci)*128 + cout]);
    }
  }
  gsync(a.bar, 1*nblk);

  // ph1: build all 6 inverse tables
  for (int L = 0; L < 6; ++L){
    const int M = a.M[L];
    for (long t = gid; t < 9L*M; t += gstride){
      int k = (int)(t / M); long i = t - (long)k*M;
      int ii = a.im[L][(long)k*M + i];
      int oo = a.om[L][(long)k*M + i];
      if (ii >= 0 && ii < a.nin[L] && oo >= 0 && oo < a.nout[L])
        a.tb[a.toff[L] + (long)k*a.nout[L] + oo] = ii;
    }
  }
  gsync(a.bar, 2*nblk);

  // ph2: c0 (1->64ch) via table
  {
    float* w_s = (float*)smem;           // 576 floats
    float* b_s = (float*)smem + 576;     // 64 floats
    for (int i = tid; i < 576; i += 512) w_s[i] = a.w_c0[i];
    if (tid < 64) b_s[tid] = a.b_c0[tid];
    __syncthreads();
    const int* tab = a.tb;               // toff[0] == 0
    for (long rr = gid; rr < (long)a.n0; rr += gstride){
      float f[9];
      #pragma unroll
      for (int k = 0; k < 9; k++){
        int gi = tab[(long)k*a.n0 + rr];
        f[k] = (gi >= 0) ? a.feats[gi] : 0.f;
      }
      uint16_t* dst = a.fbuf + rr*64;
      #pragma unroll
      for (int c0 = 0; c0 < 64; c0 += 16){
        float ac[16];
        #pragma unroll
        for (int j = 0; j < 16; j++) ac[j] = b_s[c0+j];
        #pragma unroll
        for (int k = 0; k < 9; k++){
          float fk = f[k];
          #pragma unroll
          for (int j = 0; j < 16; j++) ac[j] += fk * w_s[k*64 + c0 + j];
        }
        uint4 o0, o1;
        o0.x = pack2(ac[0],ac[1]);   o0.y = pack2(ac[2],ac[3]);
        o0.z = pack2(ac[4],ac[5]);   o0.w = pack2(ac[6],ac[7]);
        o1.x = pack2(ac[8],ac[9]);   o1.y = pack2(ac[10],ac[11]);
        o1.z = pack2(ac[12],ac[13]); o1.w = pack2(ac[14],ac[15]);
        *(uint4*)(dst + c0)     = o0;
        *(uint4*)(dst + c0 + 8) = o1;
      }
    }
  }
  gsync(a.bar, 3*nblk);

  const long wt64 = 9L*128*64, wt128 = 9L*128*128;
  // ph3: d0  (x bf16 -> out0 fp32 + bf0 bf16, relu)
  mconv_phase<64,2,true>(smem, a.wsb, 0L, a.wtb_off, a.zp_off,
                         a.b_d0, a.tb + a.toff[1], a.out0, a.bf0, a.n1, bid, nblk);
  gsync(a.bar, 4*nblk);
  // ph4: c1  (bf0 -> fbuf bf16)
  mconv_phase<128,1,false>(smem, a.wsb, a.bf0_off, a.wtb_off + wt64*2, a.zp_off,
                           a.b_c1, a.tb + a.toff[2], nullptr, a.fbuf, a.n1, bid, nblk);
  gsync(a.bar, 5*nblk);
  // ph5: d1  (fbuf -> out1 fp32 + bf1 bf16, relu)
  mconv_phase<128,2,true>(smem, a.wsb, 0L, a.wtb_off + (wt64 + wt128)*2, a.zp_off,
                          a.b_d1, a.tb + a.toff[3], a.out1, a.bf1, a.n2, bid, nblk);
  gsync(a.bar, 6*nblk);
  // ph6: c2  (bf1 -> fbuf bf16)
  mconv_phase<128,1,false>(smem, a.wsb, a.bf1_off, a.wtb_off + (wt64 + 2*wt128)*2, a.zp_off,
                           a.b_c2, a.tb + a.toff[4], nullptr, a.fbuf, a.n2, bid, nblk);
  gsync(a.bar, 7*nblk);
  // ph7: d2  (fbuf -> out2 fp32)
  mconv_phase<128,0,false>(smem, a.wsb, 0L, a.wtb_off + (wt64 + 3*wt128)*2, a.zp_off,
                           a.b_d2, a.tb + a.toff[5], a.out2, nullptr, a.n3, bid, nblk);
}

static inline long cdivl(long a, long b){ return (a + b - 1) / b; }

extern "C" void kernel_launch(void* const* d_in, const int* in_sizes, int n_in_args,
                              void* d_out, int out_size, void* d_ws, size_t ws_size,
                              hipStream_t stream) {
  const float* feats = (const float*)d_in[0];
  const float* w_c0 = (const float*)d_in[1];
  const float* b_c0 = (const float*)d_in[2];
  const int* in_c0  = (const int*)d_in[3];
  const int* out_c0 = (const int*)d_in[4];
  const float* w_d0 = (const float*)d_in[5];
  const float* b_d0 = (const float*)d_in[6];
  const int* in_d0  = (const int*)d_in[7];
  const int* out_d0 = (const int*)d_in[8];
  const float* w_c1 = (const float*)d_in[9];
  const float* b_c1 = (const float*)d_in[10];
  const int* in_c1  = (const int*)d_in[11];
  const int* out_c1 = (const int*)d_in[12];
  const float* w_d1 = (const float*)d_in[13];
  const float* b_d1 = (const float*)d_in[14];
  const int* in_d1  = (const int*)d_in[15];
  const int* out_d1 = (const int*)d_in[16];
  const float* w_c2 = (const float*)d_in[17];
  const float* b_c2 = (const float*)d_in[18];
  const int* in_c2  = (const int*)d_in[19];
  const int* out_c2 = (const int*)d_in[20];
  const float* w_d2 = (const float*)d_in[21];
  const float* b_d2 = (const float*)d_in[22];
  const int* in_d2  = (const int*)d_in[23];
  const int* out_d2 = (const int*)d_in[24];

  const int n0   = in_sizes[0];
  const int M_c0 = in_sizes[3]  / 9;
  const int M_d0 = in_sizes[7]  / 9;
  const int M_c1 = in_sizes[11] / 9;
  const int M_d1 = in_sizes[15] / 9;
  const int M_c2 = in_sizes[19] / 9;
  const int M_d2 = in_sizes[23] / 9;
  const int n1   = M_c1;
  const int n2   = M_c2;
  const int n3   = out_size/128 - n1 - n2;

  bool sane = n0 > 0 && out_size % 128 == 0 &&
              M_c0 > 0 && M_d0 > 0 && M_d1 > 0 && M_d2 > 0 &&
              n1 > 0 && n2 > 0 && n3 > 0;

  long maxElems = (long)n0*64;
  if ((long)n1*128 > maxElems) maxElems = (long)n1*128;
  if ((long)n2*128 > maxElems) maxElems = (long)n2*128;
  long fbytes = (maxElems*2 + 255)/256*256;
  long ntab   = sane ? 9L*((long)n0 + 2L*n1 + 2L*n2 + n3) : 0;
  long tbytes = (ntab*4 + 255)/256*256;
  long wt64  = 9L*128*64, wt128 = 9L*128*128;
  long wbytes = ((wt64 + 4*wt128)*2 + 255)/256*256;
  long zbytes = 256;
  long barbytes = 256;
  long b1bytes = sane ? ((long)n2*128*2 + 255)/256*256 : 0;
  long b0bytes = sane ? ((long)n1*128*2 + 255)/256*256 : 0;
  long need_full = fbytes + tbytes + wbytes + zbytes + barbytes + 256
                 + b1bytes + b0bytes;

  if (!sane || ws_size < (size_t)need_full){
    float C = (float)(16 + (int)std::min<size_t>(ws_size >> 20, (size_t)100000));
    if (!sane) C *= 1099511627776.0f;
    diag_kernel<<<cdivl(out_size,256),256,0,stream>>>((float*)d_out, out_size, C);
    return;
  }

  // ws: [ fbuf | tables x6 | wtb x5 | zero page | barrier | bf1 | bf0 ]
  uint16_t* fbuf = (uint16_t*)d_ws;
  long tab_off    = fbytes;
  long wtb_off    = fbytes + tbytes;
  long zp_off     = fbytes + tbytes + wbytes;
  long bar_off    = zp_off + zbytes;
  long bf1_off    = bar_off + barbytes + 256;
  long bf0_off    = bf1_off + b1bytes;
  const char* wsb = (const char*)d_ws;
  int* tb        = (int*)((char*)d_ws + tab_off);
  float* zp_p    = (float*)((char*)d_ws + zp_off);
  int* bar_p     = (int*)((char*)d_ws + bar_off);
  uint16_t* bf1  = (uint16_t*)((char*)d_ws + bf1_off);
  uint16_t* bf0  = (uint16_t*)((char*)d_ws + bf0_off);

  // table int offsets (contiguous, order: c0 d0 c1 d1 c2 d2)
  long t_c0 = 0;
  long t_d0 = t_c0 + 9L*n0;
  long t_c1 = t_d0 + 9L*n1;
  long t_d1 = t_c1 + 9L*n1;
  long t_c2 = t_d1 + 9L*n2;
  long t_d2 = t_c2 + 9L*n2;

  float* out2 = (float*)d_out;
  float* out1 = out2 + (long)n3*128;
  float* out0 = out1 + (long)n2*128;

  MegaArgs ma;
  ma.wsb = wsb; ma.tb = tb; ma.bar = bar_p; ma.ntab = ntab;
  ma.im[0]=in_c0;  ma.om[0]=out_c0; ma.M[0]=M_c0; ma.nin[0]=n0; ma.nout[0]=n0; ma.toff[0]=t_c0;
  ma.im[1]=in_d0;  ma.om[1]=out_d0; ma.M[1]=M_d0; ma.nin[1]=n0; ma.nout[1]=n1; ma.toff[1]=t_d0;
  ma.im[2]=in_c1;  ma.om[2]=out_c1; ma.M[2]=M_c1; ma.nin[2]=n1; ma.nout[2]=n1; ma.toff[2]=t_c1;
  ma.im[3]=in_d1;  ma.om[3]=out_d1; ma.M[3]=M_d1; ma.nin[3]=n1; ma.nout[3]=n2; ma.toff[3]=t_d1;
  ma.im[4]=in_c2;  ma.om[4]=out_c2; ma.M[4]=M_c2; ma.nin[4]=n2; ma.nout[4]=n2; ma.toff[4]=t_c2;
  ma.im[5]=in_d2;  ma.om[5]=out_d2; ma.M[5]=M_d2; ma.nin[5]=n2; ma.nout[5]=n3; ma.toff[5]=t_d2;
  ma.w[0]=w_d0; ma.w[1]=w_c1; ma.w[2]=w_d1; ma.w[3]=w_c2; ma.w[4]=w_d2;
  ma.wtotal = wt64 + 4*wt128;
  ma.wb = (uint16_t*)((char*)d_ws + wtb_off);
  ma.feats = feats; ma.w_c0 = w_c0; ma.b_c0 = b_c0;
  ma.fbuf = fbuf;
  ma.n0 = n0; ma.n1 = n1; ma.n2 = n2; ma.n3 = n3;
  ma.wtb_off = wtb_off; ma.zp_off = zp_off;
  ma.bf0_off = bf0_off; ma.bf1_off = bf1_off;
  ma.b_d0 = b_d0; ma.b_c1 = b_c1; ma.b_d1 = b_d1; ma.b_c2 = b_c2; ma.b_d2 = b_d2;
  ma.out0 = out0; ma.out1 = out1; ma.out2 = out2;
  ma.bf0 = bf0; ma.bf1 = bf1;

  init_bar_kernel<<<1,256,0,stream>>>(bar_p, zp_p);
  mega_kernel<<<512,512,0,stream>>>(ma);
}

// Round 7
// 1319.946 us; speedup vs baseline: 1.0755x; 1.0755x over previous
//
#include <hip/hip_runtime.h>
#include <stdint.h>
#include <algorithm>

// Sparse conv encoder on MI355X. R12: mega-kernel with FIXED barrier coherence.
// R11 failure diagnosed from counters: gsync's __threadfence() (agent seq-cst)
// lowers to buffer_wbl2 + buffer_inv on gfx950; per-block, both-sides, all 7
// barriers => ~3600 L2 invalidations => entire 2GB staging working set served
// from HBM (FETCH 712MB + WRITE 1.24GB @ 1.6TB/s over 1250us - arithmetic
// closes). Fix: dataflow-derived protocol:
//   - ALL barriers: producer release fence (vmcnt drain + wbl2) per block
//     (redundant wbl2 on clean L2 = no-op; last-arriver-per-XCD covers all).
//   - ONLY barriers {2,5,7} add consumer acquire (buffer_inv): tables
//     (W ph0, W ph1, R ph2+) and fbuf rewrites (R ph3 -> W ph4 -> R ph5;
//     R ph5 -> W ph6 -> R ph7). All other regions are write-once/first-read;
//     byte-granular L2 dirty masks merge partial lines (R11 passed => proven).
//   - Poll: relaxed agent-scope atomic load + s_sleep(32) (~0.85us) backoff,
//     not the R11 atomicAdd(bar,0) hammer.
// mconv body byte-identical to R10 (487us-proven). Everything else = R11.
// Predict: mega 1250 -> ~400-450us, FETCH ~300MB, WRITE ~300MB, MfmaUtil ~13%,
// total -> ~440-480us. If >=491: revert to R10 multi-dispatch next round.

#define DI __device__ __forceinline__

typedef __attribute__((ext_vector_type(8))) short bf16x8;
typedef __attribute__((ext_vector_type(4))) float f32x4;

DI uint16_t f2bf(float x){
  union{float f;uint32_t i;}v; v.f=x;
  uint32_t r = v.i + 0x7fffu + ((v.i>>16)&1u);
  return (uint16_t)(r>>16);
}
DI uint32_t pack2(float a, float b){
  return (uint32_t)f2bf(a) | ((uint32_t)f2bf(b) << 16);
}
DI void gload16(const void* g, void* l){
  __builtin_amdgcn_global_load_lds(
      (const __attribute__((address_space(1))) void*)g,
      (__attribute__((address_space(3))) void*)l, 16, 0, 0);
}

__global__ __launch_bounds__(256) void diag_kernel(float* __restrict__ out, long n, float c){
  long i = (long)blockIdx.x*256 + threadIdx.x;
  if (i < n) out[i] = c;
}

// zero barrier counters + 256B zero page (must precede mega_kernel)
__global__ __launch_bounds__(256) void init_bar_kernel(int* __restrict__ bar,
                                                       float* __restrict__ zp){
  int t = threadIdx.x;
  if (t < 64) bar[t] = 0;
  if (t >= 64 && t < 128) zp[t-64] = 0.f;
}

struct MegaArgs {
  const char* wsb;
  int* tb;
  int* bar;
  long ntab;
  const int* im[6]; const int* om[6];
  int   M[6]; int nin[6]; int nout[6];
  long  toff[6];
  const float* w[5];           // prep_w sources (d0,c1,d1,c2,d2)
  long wtotal;
  uint16_t* wb;
  const float* feats; const float* w_c0; const float* b_c0;
  uint16_t* fbuf;
  int n0, n1, n2, n3;
  long wtb_off, zp_off, bf0_off, bf1_off;
  const float *b_d0, *b_c1, *b_d1, *b_c2, *b_d2;
  float *out0, *out1, *out2;
  uint16_t *bf0, *bf1;
};

// Grid barrier, release-only: producer flush (vmcnt drain + wbl2), relaxed
// arrival + relaxed poll w/ sleep backoff. NO consumer invalidate.
DI void gsync_rel(int* bar, int target){
  __syncthreads();                                   // block arrived, stores issued
  if (threadIdx.x == 0){
    __builtin_amdgcn_fence(__ATOMIC_RELEASE, "agent");   // waitcnt + buffer_wbl2
    __hip_atomic_fetch_add(bar, 1, __ATOMIC_RELAXED, __HIP_MEMORY_SCOPE_AGENT);
    int spins = 0;
    while (__hip_atomic_load(bar, __ATOMIC_RELAXED, __HIP_MEMORY_SCOPE_AGENT) < target){
      __builtin_amdgcn_s_sleep(32);
      if (++spins > 2000000) break;                  // safety: fail loud, never hang
    }
    asm volatile("" ::: "memory");                   // compiler: no load hoisting
  }
  __syncthreads();
}

// Grid barrier with consumer acquire (buffer_inv + L1 inv) — only where a
// region is read-rewritten-reread across the barrier.
DI void gsync_acq(int* bar, int target){
  __syncthreads();
  if (threadIdx.x == 0){
    __builtin_amdgcn_fence(__ATOMIC_RELEASE, "agent");
    __hip_atomic_fetch_add(bar, 1, __ATOMIC_RELAXED, __HIP_MEMORY_SCOPE_AGENT);
    int spins = 0;
    while (__hip_atomic_load(bar, __ATOMIC_RELAXED, __HIP_MEMORY_SCOPE_AGENT) < target){
      __builtin_amdgcn_s_sleep(32);
      if (++spins > 2000000) break;
    }
    __builtin_amdgcn_fence(__ATOMIC_ACQUIRE, "agent");   // buffer_inv (+L1)
  }
  __syncthreads();
}

// Flattened-K gathered GEMM phase, verbatim R10 pipeline inside a tile loop.
// BM=128 x BN=128, BK=64, 8 waves (4x2), A 3buf depth-2, B 2buf depth-1.
template<int CIN, int OUTMODE, bool RELU>
DI void mconv_phase(uint8_t* smem, const char* ws_base, long in_off,
                    long wtb_off, long zp_off,
                    const float* __restrict__ bias, const int* __restrict__ tab,
                    float* __restrict__ outf, uint16_t* __restrict__ outb,
                    int n_out, int bid, int nblk){
  constexpr int NS = 9*CIN/64;
  uint16_t (*ab)[128*64] = (uint16_t(*)[128*64])smem;              // 3 x 16KB
  uint16_t (*bb)[128*64] = (uint16_t(*)[128*64])(smem + 3*16384);  // 2 x 16KB
  const int tid = threadIdx.x;

  // balanced bijective XCD-clustered tile split: adjacent tiles -> same XCD
  const int T = (n_out + 127) >> 7;
  const int q = T / nblk, r = T % nblk;
  const int sb = (bid & 7)*(nblk >> 3) + (bid >> 3);
  const int t0 = (sb < r) ? sb*(q+1) : r*(q+1) + (sb - r)*q;
  const int t1 = t0 + ((sb < r) ? (q+1) : q);

  const int r0 = tid >> 3, sg = tid & 7;
  const int ss0 = sg ^ (r0 & 7);
  const uint32_t offB = (uint32_t)(wtb_off + ((long)r0*CIN + ss0*8)*2);

  const int lane = tid & 63, wv = tid >> 6;
  const int wr = (wv >> 1) << 5;    // 4 row-waves x 32
  const int wc = (wv & 1) << 6;     // 2 col-waves x 64
  const int l16 = lane & 15, quad = lane >> 4;

  float bv[4];
  #pragma unroll
  for (int ct = 0; ct < 4; ++ct) bv[ct] = bias[wc + (ct<<4) + l16];

  for (int tile = t0; tile < t1; ++tile){
    __builtin_amdgcn_s_barrier();   // protect LDS from prior-tile stragglers
    const long rb = (long)tile * 128;

    uint32_t offA[2][9];
    #pragma unroll
    for (int kk = 0; kk < 9; ++kk){
      #pragma unroll
      for (int it = 0; it < 2; ++it){
        long row = rb + it*64 + r0;
        int gi = (row < (long)n_out) ? tab[(long)kk*n_out + row] : -1;
        offA[it][kk] = (gi >= 0)
            ? (uint32_t)(in_off + (long)gi*(CIN*2) + ss0*16)
            : (uint32_t)(zp_off + ss0*16);
      }
    }

    f32x4 acc[2][4];
    #pragma unroll
    for (int i = 0; i < 2; i++)
      #pragma unroll
      for (int j = 0; j < 4; j++)
        acc[i][j] = (f32x4){0.f,0.f,0.f,0.f};

    auto stage_a = [&](int step, int nb){
      const int kk  = (CIN == 64) ? step : (step >> 1);
      const int c0b = (CIN == 64) ? 0 : ((step & 1) * 128);
      #pragma unroll
      for (int it = 0; it < 2; ++it)
        gload16(ws_base + offA[it][kk] + c0b, &ab[nb][(it*512+tid)*8]);
    };
    auto stage_b = [&](int step, int nb){
      const int kk  = (CIN == 64) ? step : (step >> 1);
      const int c0b = (CIN == 64) ? 0 : ((step & 1) * 128);
      const uint32_t base = offB + (uint32_t)((long)kk*128*CIN*2 + c0b);
      #pragma unroll
      for (int it = 0; it < 2; ++it)
        gload16(ws_base + base + it*(64*CIN*2), &bb[nb][(it*512+tid)*8]);
    };
    auto compute = [&](int na, int nb){
      const uint16_t* A  = &ab[na][0];
      const uint16_t* Bm = &bb[nb][0];
      __builtin_amdgcn_s_setprio(1);
      #pragma unroll
      for (int ch = 0; ch < 2; ++ch){
        const int xs = ((((ch << 2) + quad) ^ (l16 & 7)) << 3);
        bf16x8 af[2], bfr[4];
        #pragma unroll
        for (int u = 0; u < 2; ++u)
          af[u]  = *(const bf16x8*)&A [((wr + (u<<4) + l16) << 6) + xs];
        #pragma unroll
        for (int u = 0; u < 4; ++u)
          bfr[u] = *(const bf16x8*)&Bm[((wc + (u<<4) + l16) << 6) + xs];
        #pragma unroll
        for (int rt = 0; rt < 2; ++rt)
          #pragma unroll
          for (int ct = 0; ct < 4; ++ct)
            acc[rt][ct] = __builtin_amdgcn_mfma_f32_16x16x32_bf16(
                af[rt], bfr[ct], acc[rt][ct], 0, 0, 0);
      }
      __builtin_amdgcn_s_setprio(0);
    };

    stage_a(0, 0);
    stage_a(1, 1);
    stage_b(0, 0);
    #pragma unroll
    for (int t = 0; t < NS; ++t){
      if (t + 2 < NS) stage_a(t+2, (t+2)%3);
      if (t + 1 < NS) stage_b(t+1, (t+1)&1);
      if (t + 2 < NS){
        asm volatile("s_waitcnt vmcnt(4)" ::: "memory");
      } else if (t + 1 < NS){
        asm volatile("s_waitcnt vmcnt(2)" ::: "memory");
      } else {
        asm volatile("s_waitcnt vmcnt(0)" ::: "memory");
      }
      __builtin_amdgcn_sched_barrier(0);
      __builtin_amdgcn_s_barrier();
      compute(t%3, t&1);
      if (t + 1 < NS)
        __builtin_amdgcn_s_barrier();
    }

    #pragma unroll
    for (int ct = 0; ct < 4; ++ct){
      const int cout = wc + (ct<<4) + l16;
      #pragma unroll
      for (int rt = 0; rt < 2; ++rt){
        #pragma unroll
        for (int rr2 = 0; rr2 < 4; ++rr2){
          long row = rb + wr + (rt<<4) + (quad<<2) + rr2;
          if (row < (long)n_out){
            float v = acc[rt][ct][rr2] + bv[ct];
            if (RELU) v = v > 0.f ? v : 0.f;
            if constexpr (OUTMODE == 0 || OUTMODE == 2) outf[row*128 + cout] = v;
            if constexpr (OUTMODE == 1 || OUTMODE == 2) outb[row*128 + cout] = f2bf(v);
          }
        }
      }
    }
  }
}

__global__ __launch_bounds__(512,4) void mega_kernel(MegaArgs a){
  __shared__ __align__(16) uint8_t smem[81920];
  const int tid = threadIdx.x, bid = blockIdx.x;
  const int nblk = gridDim.x;
  const long gid = (long)bid*512 + tid;
  const long gstride = (long)nblk*512;

  // ph0: tables = -1, weight transposes (zero page done by init_bar_kernel)
  for (long i = gid; i < a.ntab; i += gstride) a.tb[i] = -1;
  {
    const long wt64 = 9L*128*64, wt128 = 9L*128*128;
    for (long idx = gid; idx < a.wtotal; idx += gstride){
      int L; long rr; int cin;
      if (idx < wt64){ L = 0; rr = idx; cin = 64; }
      else { long j = idx - wt64; L = 1 + (int)(j / wt128); rr = j % wt128; cin = 128; }
      const float* w = a.w[L];
      int k = (int)(rr / (128*cin));
      int rem = (int)(rr % (128*cin));
      int cout = rem / cin, ci = rem % cin;
      a.wb[idx] = f2bf(w[((long)k*cin + ci)*128 + cout]);
    }
  }
  gsync_rel(a.bar, 1*nblk);

  // ph1: build all 6 inverse tables (writes merge into ph0's -1 lines;
  // byte-granular L2 dirty masks make partial-line merges correct)
  for (int L = 0; L < 6; ++L){
    const int M = a.M[L];
    for (long t = gid; t < 9L*M; t += gstride){
      int k = (int)(t / M); long i = t - (long)k*M;
      int ii = a.im[L][(long)k*M + i];
      int oo = a.om[L][(long)k*M + i];
      if (ii >= 0 && ii < a.nin[L] && oo >= 0 && oo < a.nout[L])
        a.tb[a.toff[L] + (long)k*a.nout[L] + oo] = ii;
    }
  }
  gsync_acq(a.bar, 2*nblk);   // ACQ: tables were W(ph0)->W(ph1)->R(ph2+);
                              // ph0 writers hold stale all--1 clean copies

  // ph2: c0 (1->64ch) via table
  {
    float* w_s = (float*)smem;           // 576 floats
    float* b_s = (float*)smem + 576;     // 64 floats
    for (int i = tid; i < 576; i += 512) w_s[i] = a.w_c0[i];
    if (tid < 64) b_s[tid] = a.b_c0[tid];
    __syncthreads();
    const int* tab = a.tb;               // toff[0] == 0
    for (long rr = gid; rr < (long)a.n0; rr += gstride){
      float f[9];
      #pragma unroll
      for (int k = 0; k < 9; k++){
        int gi = tab[(long)k*a.n0 + rr];
        f[k] = (gi >= 0) ? a.feats[gi] : 0.f;
      }
      uint16_t* dst = a.fbuf + rr*64;
      #pragma unroll
      for (int c0 = 0; c0 < 64; c0 += 16){
        float ac[16];
        #pragma unroll
        for (int j = 0; j < 16; j++) ac[j] = b_s[c0+j];
        #pragma unroll
        for (int k = 0; k < 9; k++){
          float fk = f[k];
          #pragma unroll
          for (int j = 0; j < 16; j++) ac[j] += fk * w_s[k*64 + c0 + j];
        }
        uint4 o0, o1;
        o0.x = pack2(ac[0],ac[1]);   o0.y = pack2(ac[2],ac[3]);
        o0.z = pack2(ac[4],ac[5]);   o0.w = pack2(ac[6],ac[7]);
        o1.x = pack2(ac[8],ac[9]);   o1.y = pack2(ac[10],ac[11]);
        o1.z = pack2(ac[12],ac[13]); o1.w = pack2(ac[14],ac[15]);
        *(uint4*)(dst + c0)     = o0;
        *(uint4*)(dst + c0 + 8) = o1;
      }
    }
  }
  gsync_rel(a.bar, 3*nblk);   // fbuf first-read in ph3: no stale copies exist

  const long wt64 = 9L*128*64, wt128 = 9L*128*128;
  // ph3: d0  (x bf16 -> out0 fp32 + bf0 bf16, relu)
  mconv_phase<64,2,true>(smem, a.wsb, 0L, a.wtb_off, a.zp_off,
                         a.b_d0, a.tb + a.toff[1], a.out0, a.bf0, a.n1, bid, nblk);
  gsync_rel(a.bar, 4*nblk);   // bf0 first-read in ph4: no stale copies
  // ph4: c1  (bf0 -> fbuf bf16)
  mconv_phase<128,1,false>(smem, a.wsb, a.bf0_off, a.wtb_off + wt64*2, a.zp_off,
                           a.b_c1, a.tb + a.toff[2], nullptr, a.fbuf, a.n1, bid, nblk);
  gsync_acq(a.bar, 5*nblk);   // ACQ: fbuf R(ph3) -> W(ph4) -> R(ph5)
  // ph5: d1  (fbuf -> out1 fp32 + bf1 bf16, relu)
  mconv_phase<128,2,true>(smem, a.wsb, 0L, a.wtb_off + (wt64 + wt128)*2, a.zp_off,
                          a.b_d1, a.tb + a.toff[3], a.out1, a.bf1, a.n2, bid, nblk);
  gsync_rel(a.bar, 6*nblk);   // bf1 first-read in ph6: no stale copies
  // ph6: c2  (bf1 -> fbuf bf16)
  mconv_phase<128,1,false>(smem, a.wsb, a.bf1_off, a.wtb_off + (wt64 + 2*wt128)*2, a.zp_off,
                           a.b_c2, a.tb + a.toff[4], nullptr, a.fbuf, a.n2, bid, nblk);
  gsync_acq(a.bar, 7*nblk);   // ACQ: fbuf R(ph5) -> W(ph6) -> R(ph7)
  // ph7: d2  (fbuf -> out2 fp32)
  mconv_phase<128,0,false>(smem, a.wsb, 0L, a.wtb_off + (wt64 + 3*wt128)*2, a.zp_off,
                           a.b_d2, a.tb + a.toff[5], a.out2, nullptr, a.n3, bid, nblk);
}

static inline long cdivl(long a, long b){ return (a + b - 1) / b; }

extern "C" void kernel_launch(void* const* d_in, const int* in_sizes, int n_in_args,
                              void* d_out, int out_size, void* d_ws, size_t ws_size,
                              hipStream_t stream) {
  const float* feats = (const float*)d_in[0];
  const float* w_c0 = (const float*)d_in[1];
  const float* b_c0 = (const float*)d_in[2];
  const int* in_c0  = (const int*)d_in[3];
  const int* out_c0 = (const int*)d_in[4];
  const float* w_d0 = (const float*)d_in[5];
  const float* b_d0 = (const float*)d_in[6];
  const int* in_d0  = (const int*)d_in[7];
  const int* out_d0 = (const int*)d_in[8];
  const float* w_c1 = (const float*)d_in[9];
  const float* b_c1 = (const float*)d_in[10];
  const int* in_c1  = (const int*)d_in[11];
  const int* out_c1 = (const int*)d_in[12];
  const float* w_d1 = (const float*)d_in[13];
  const float* b_d1 = (const float*)d_in[14];
  const int* in_d1  = (const int*)d_in[15];
  const int* out_d1 = (const int*)d_in[16];
  const float* w_c2 = (const float*)d_in[17];
  const float* b_c2 = (const float*)d_in[18];
  const int* in_c2  = (const int*)d_in[19];
  const int* out_c2 = (const int*)d_in[20];
  const float* w_d2 = (const float*)d_in[21];
  const float* b_d2 = (const float*)d_in[22];
  const int* in_d2  = (const int*)d_in[23];
  const int* out_d2 = (const int*)d_in[24];

  const int n0   = in_sizes[0];
  const int M_c0 = in_sizes[3]  / 9;
  const int M_d0 = in_sizes[7]  / 9;
  const int M_c1 = in_sizes[11] / 9;
  const int M_d1 = in_sizes[15] / 9;
  const int M_c2 = in_sizes[19] / 9;
  const int M_d2 = in_sizes[23] / 9;
  const int n1   = M_c1;
  const int n2   = M_c2;
  const int n3   = out_size/128 - n1 - n2;

  bool sane = n0 > 0 && out_size % 128 == 0 &&
              M_c0 > 0 && M_d0 > 0 && M_d1 > 0 && M_d2 > 0 &&
              n1 > 0 && n2 > 0 && n3 > 0;

  long maxElems = (long)n0*64;
  if ((long)n1*128 > maxElems) maxElems = (long)n1*128;
  if ((long)n2*128 > maxElems) maxElems = (long)n2*128;
  long fbytes = (maxElems*2 + 255)/256*256;
  long ntab   = sane ? 9L*((long)n0 + 2L*n1 + 2L*n2 + n3) : 0;
  long tbytes = (ntab*4 + 255)/256*256;
  long wt64  = 9L*128*64, wt128 = 9L*128*128;
  long wbytes = ((wt64 + 4*wt128)*2 + 255)/256*256;
  long zbytes = 256;
  long barbytes = 256;
  long b1bytes = sane ? ((long)n2*128*2 + 255)/256*256 : 0;
  long b0bytes = sane ? ((long)n1*128*2 + 255)/256*256 : 0;
  long need_full = fbytes + tbytes + wbytes + zbytes + barbytes + 256
                 + b1bytes + b0bytes;

  if (!sane || ws_size < (size_t)need_full){
    float C = (float)(16 + (int)std::min<size_t>(ws_size >> 20, (size_t)100000));
    if (!sane) C *= 1099511627776.0f;
    diag_kernel<<<cdivl(out_size,256),256,0,stream>>>((float*)d_out, out_size, C);
    return;
  }

  // ws: [ fbuf | tables x6 | wtb x5 | zero page | barrier | bf1 | bf0 ]
  uint16_t* fbuf = (uint16_t*)d_ws;
  long tab_off    = fbytes;
  long wtb_off    = fbytes + tbytes;
  long zp_off     = fbytes + tbytes + wbytes;
  long bar_off    = zp_off + zbytes;
  long bf1_off    = bar_off + barbytes + 256;
  long bf0_off    = bf1_off + b1bytes;
  const char* wsb = (const char*)d_ws;
  int* tb        = (int*)((char*)d_ws + tab_off);
  float* zp_p    = (float*)((char*)d_ws + zp_off);
  int* bar_p     = (int*)((char*)d_ws + bar_off);
  uint16_t* bf1  = (uint16_t*)((char*)d_ws + bf1_off);
  uint16_t* bf0  = (uint16_t*)((char*)d_ws + bf0_off);

  // table int offsets (contiguous, order: c0 d0 c1 d1 c2 d2)
  long t_c0 = 0;
  long t_d0 = t_c0 + 9L*n0;
  long t_c1 = t_d0 + 9L*n1;
  long t_d1 = t_c1 + 9L*n1;
  long t_c2 = t_d1 + 9L*n2;
  long t_d2 = t_c2 + 9L*n2;

  float* out2 = (float*)d_out;
  float* out1 = out2 + (long)n3*128;
  float* out0 = out1 + (long)n2*128;

  MegaArgs ma;
  ma.wsb = wsb; ma.tb = tb; ma.bar = bar_p; ma.ntab = ntab;
  ma.im[0]=in_c0;  ma.om[0]=out_c0; ma.M[0]=M_c0; ma.nin[0]=n0; ma.nout[0]=n0; ma.toff[0]=t_c0;
  ma.im[1]=in_d0;  ma.om[1]=out_d0; ma.M[1]=M_d0; ma.nin[1]=n0; ma.nout[1]=n1; ma.toff[1]=t_d0;
  ma.im[2]=in_c1;  ma.om[2]=out_c1; ma.M[2]=M_c1; ma.nin[2]=n1; ma.nout[2]=n1; ma.toff[2]=t_c1;
  ma.im[3]=in_d1;  ma.om[3]=out_d1; ma.M[3]=M_d1; ma.nin[3]=n1; ma.nout[3]=n2; ma.toff[3]=t_d1;
  ma.im[4]=in_c2;  ma.om[4]=out_c2; ma.M[4]=M_c2; ma.nin[4]=n2; ma.nout[4]=n2; ma.toff[4]=t_c2;
  ma.im[5]=in_d2;  ma.om[5]=out_d2; ma.M[5]=M_d2; ma.nin[5]=n2; ma.nout[5]=n3; ma.toff[5]=t_d2;
  ma.w[0]=w_d0; ma.w[1]=w_c1; ma.w[2]=w_d1; ma.w[3]=w_c2; ma.w[4]=w_d2;
  ma.wtotal = wt64 + 4*wt128;
  ma.wb = (uint16_t*)((char*)d_ws + wtb_off);
  ma.feats = feats; ma.w_c0 = w_c0; ma.b_c0 = b_c0;
  ma.fbuf = fbuf;
  ma.n0 = n0; ma.n1 = n1; ma.n2 = n2; ma.n3 = n3;
  ma.wtb_off = wtb_off; ma.zp_off = zp_off;
  ma.bf0_off = bf0_off; ma.bf1_off = bf1_off;
  ma.b_d0 = b_d0; ma.b_c1 = b_c1; ma.b_d1 = b_d1; ma.b_c2 = b_c2; ma.b_d2 = b_d2;
  ma.out0 = out0; ma.out1 = out1; ma.out2 = out2;
  ma.bf0 = bf0; ma.bf1 = bf1;

  init_bar_kernel<<<1,256,0,stream>>>(bar_p, zp_p);
  mega_kernel<<<512,512,0,stream>>>(ma);
}

// Round 9
// 503.326 us; speedup vs baseline: 2.8205x; 2.6224x over previous
//
#include <hip/hip_runtime.h>
#include <stdint.h>
#include <algorithm>

// Sparse conv encoder on MI355X. R14: revert to the proven R8 multi-dispatch
// structure (487us session best) after the mega-kernel arc failed
// (R11 per-block fence L2-flush amplification 3x; R12 acquire-removal null;
// R13 elected-fence container crash on unverifiable asm). Safe consolidation
// on top: (1) table init via hipMemsetAsync 0xFF (int -1) + zero page via
// memset 0 (SDMA, graph-capturable) -- replaces init kernel; (2) build_all +
// prep_all fused into one grid-stride kernel. 6 kernel dispatches + 2 memsets.
// mconv2 byte-equivalent to R8's proven kernel: flattened-K gather GEMM
// (K=9*CIN, BK=64), BM=128xBN=128, 512 thr (8 waves 4x2, wave 32x64),
// 2 LDS bufs each for A/B (64KB -> 2 blocks/CU), global_load_lds 16B,
// source-side XOR seg swizzle (0 bank conflicts), reg-precomputed gather
// offsets w/ zero-page fold, counted s_waitcnt vmcnt(4), sched_barrier,
// setprio around MFMA, bijective XCD chunk swizzle.
// Predict: total ~465-485us; mconv LDS ~65.5KB, VGPR ~88, conflicts 0.
// If >=490: consolidation exhausted; mconv latency plateau is the floor axis.

#define DI __device__ __forceinline__

typedef __attribute__((ext_vector_type(8))) short bf16x8;
typedef __attribute__((ext_vector_type(4))) float f32x4;

DI uint16_t f2bf(float x){
  union{float f;uint32_t i;}v; v.f=x;
  uint32_t r = v.i + 0x7fffu + ((v.i>>16)&1u);
  return (uint16_t)(r>>16);
}
DI uint32_t pack2(float a, float b){
  return (uint32_t)f2bf(a) | ((uint32_t)f2bf(b) << 16);
}
DI void gload16(const void* g, void* l){
  __builtin_amdgcn_global_load_lds(
      (const __attribute__((address_space(1))) void*)g,
      (__attribute__((address_space(3))) void*)l, 16, 0, 0);
}

__global__ __launch_bounds__(256) void diag_kernel(float* __restrict__ out, long n, float c){
  long i = (long)blockIdx.x*256 + threadIdx.x;
  if (i < n) out[i] = c;
}

struct PBArgs {
  const float* w[5];       // prep sources d0,c1,d1,c2,d2
  uint16_t* wb;            // contiguous wtb dst
  long wtotal;             // wt64 + 4*wt128
  const int* im[6]; const int* om[6];
  int M[6]; int nin[6]; int nout[6];
  long toff[6];            // int offsets into table base
  long bcum[7];            // cumulative 9*M prefix (bcum[0]=0)
  int* tb;
  long total;              // wtotal + bcum[6]
};

// Fused: weight transposes (items [0,wtotal)) + inverse-table scatter
// (items [wtotal, total)). Tables pre-filled with -1 by hipMemsetAsync.
__global__ __launch_bounds__(256) void prep_build_kernel(PBArgs a){
  const long wt64 = 9L*128*64, wt128 = 9L*128*128;
  const long gstride = (long)gridDim.x*256;
  for (long i = (long)blockIdx.x*256 + threadIdx.x; i < a.total; i += gstride){
    if (i < a.wtotal){
      int L; long rr; int cin;
      if (i < wt64){ L = 0; rr = i; cin = 64; }
      else { long j = i - wt64; L = 1 + (int)(j / wt128); rr = j % wt128; cin = 128; }
      const float* w = a.w[L];
      int k = (int)(rr / (128*cin));
      int rem = (int)(rr % (128*cin));
      int cout = rem / cin, ci = rem % cin;
      a.wb[i] = f2bf(w[((long)k*cin + ci)*128 + cout]);
    } else {
      long j = i - a.wtotal;
      int L = 0;
      while (L < 5 && j >= a.bcum[L+1]) ++L;
      j -= a.bcum[L];
      const int M = a.M[L];
      int k = (int)(j / M);
      long t = j - (long)k*M;
      int ii = a.im[L][(long)k*M + t];
      int oo = a.om[L][(long)k*M + t];
      if (ii >= 0 && ii < a.nin[L] && oo >= 0 && oo < a.nout[L])
        a.tb[a.toff[L] + (long)k*a.nout[L] + oo] = ii;
    }
  }
}

// c0 (1->64 ch) via table: thread = row; 9 table reads + 9 cached gathers + FMA.
__global__ __launch_bounds__(256) void c0_tab_kernel(
    const float* __restrict__ feats, const float* __restrict__ w,
    const float* __restrict__ bias, const int* __restrict__ tab,
    uint16_t* __restrict__ out, int n_out){
  __shared__ float w_s[576];
  __shared__ float b_s[64];
  const int tid = threadIdx.x;
  for (int i = tid; i < 576; i += 256) w_s[i] = w[i];
  if (tid < 64) b_s[tid] = bias[tid];
  __syncthreads();
  long r = (long)blockIdx.x*256 + tid;
  if (r >= n_out) return;
  float f[9];
  #pragma unroll
  for (int k = 0; k < 9; k++){
    int gi = tab[(long)k*n_out + r];
    f[k] = (gi >= 0) ? feats[gi] : 0.f;
  }
  uint16_t* dst = out + r*64;
  #pragma unroll
  for (int c0 = 0; c0 < 64; c0 += 16){
    float a[16];
    #pragma unroll
    for (int j = 0; j < 16; j++) a[j] = b_s[c0+j];
    #pragma unroll
    for (int k = 0; k < 9; k++){
      float fk = f[k];
      #pragma unroll
      for (int j = 0; j < 16; j++) a[j] += fk * w_s[k*64 + c0 + j];
    }
    uint4 o0, o1;
    o0.x = pack2(a[0],a[1]);   o0.y = pack2(a[2],a[3]);
    o0.z = pack2(a[4],a[5]);   o0.w = pack2(a[6],a[7]);
    o1.x = pack2(a[8],a[9]);   o1.y = pack2(a[10],a[11]);
    o1.z = pack2(a[12],a[13]); o1.w = pack2(a[14],a[15]);
    *(uint4*)(dst + c0)     = o0;
    *(uint4*)(dst + c0 + 8) = o1;
  }
}

// Flattened-K gathered GEMM, BM=128 x BN=128, BK=64, 512 thr (8 waves 4x2,
// wave tile 32x64), 2 blocks/CU (64KB LDS). R8-proven counted-vmcnt pipeline.
// Input always bf16 [n_in][CIN] inside ws at in_off.
// OUTMODE: 0 = fp32 only; 1 = bf16 only; 2 = both.
template<int CIN, int OUTMODE, bool RELU>
__global__ __launch_bounds__(512,4) void mconv2_kernel(
    const char* __restrict__ ws_base, long in_off, long wtb_off, long zp_off,
    const float* __restrict__ bias, const int* __restrict__ tab,
    float* __restrict__ outf, uint16_t* __restrict__ outb, int n_out){
  constexpr int NS = 9*CIN/64;                       // K-steps of 64
  __shared__ __align__(16) uint16_t ab[2][128*64];   // A: 128 rows x BK
  __shared__ __align__(16) uint16_t bb[2][128*64];   // B: 128 couts x BK

  const int tid = threadIdx.x;
  // bijective XCD-chunked swizzle (m204) for gather L2 locality
  const int nwg = gridDim.x, orig = blockIdx.x;
  const int q = nwg >> 3, rr = nwg & 7, xcd = orig & 7, pos = orig >> 3;
  const int wg = (xcd < rr ? xcd*(q+1) : rr*(q+1) + (xcd-rr)*q) + pos;
  const long rb = (long)wg * 128;

  const int r0 = tid >> 3, sg = tid & 7;
  const int ss0 = sg ^ (r0 & 7);       // r1=r0+64 -> same &7 -> same swizzle

  // A gather offsets: ws-relative uint32, zero-page select folded.
  uint32_t offA[2][9];
  #pragma unroll
  for (int kk = 0; kk < 9; ++kk){
    #pragma unroll
    for (int it = 0; it < 2; ++it){
      long row = rb + it*64 + r0;
      int gi = (row < (long)n_out) ? tab[(long)kk*n_out + row] : -1;
      offA[it][kk] = (gi >= 0)
          ? (uint32_t)(in_off + (long)gi*(CIN*2) + ss0*16)
          : (uint32_t)(zp_off + ss0*16);
    }
  }
  const uint32_t offB = (uint32_t)(wtb_off + ((long)r0*CIN + ss0*8)*2);

  const int lane = tid & 63;
  const int wv = tid >> 6;
  const int wr = (wv >> 1) << 5;    // 4 row-waves x 32
  const int wc = (wv & 1) << 6;     // 2 col-waves x 64
  const int l16 = lane & 15, quad = lane >> 4;

  // preload bias so the K-loop has exactly 4 VMEM instrs/wave/step
  float bv[4];
  #pragma unroll
  for (int ct = 0; ct < 4; ++ct) bv[ct] = bias[wc + (ct<<4) + l16];

  f32x4 acc[2][4];
  #pragma unroll
  for (int i = 0; i < 2; i++)
    #pragma unroll
    for (int j = 0; j < 4; j++)
      acc[i][j] = (f32x4){0.f,0.f,0.f,0.f};

  auto stage_a = [&](int step, int nb){
    const int kk  = (CIN == 64) ? step : (step >> 1);
    const int c0b = (CIN == 64) ? 0 : ((step & 1) * 128);
    #pragma unroll
    for (int it = 0; it < 2; ++it)
      gload16(ws_base + offA[it][kk] + c0b, &ab[nb][(it*512+tid)*8]);
  };
  auto stage_b = [&](int step, int nb){
    const int kk  = (CIN == 64) ? step : (step >> 1);
    const int c0b = (CIN == 64) ? 0 : ((step & 1) * 128);
    const uint32_t base = offB + (uint32_t)((long)kk*128*CIN*2 + c0b);
    #pragma unroll
    for (int it = 0; it < 2; ++it)
      gload16(ws_base + base + it*(64*CIN*2), &bb[nb][(it*512+tid)*8]);
  };
  auto compute = [&](int nb){
    const uint16_t* A  = &ab[nb][0];
    const uint16_t* Bm = &bb[nb][0];
    __builtin_amdgcn_s_setprio(1);
    #pragma unroll
    for (int ch = 0; ch < 2; ++ch){
      // row&7 == l16&7 for every fragment row (wr,wc,u*16 are 0 mod 8)
      const int xs = ((((ch << 2) + quad) ^ (l16 & 7)) << 3);
      bf16x8 af[2], bfr[4];
      #pragma unroll
      for (int u = 0; u < 2; ++u)
        af[u]  = *(const bf16x8*)&A [((wr + (u<<4) + l16) << 6) + xs];
      #pragma unroll
      for (int u = 0; u < 4; ++u)
        bfr[u] = *(const bf16x8*)&Bm[((wc + (u<<4) + l16) << 6) + xs];
      #pragma unroll
      for (int rt = 0; rt < 2; ++rt)
        #pragma unroll
        for (int ct = 0; ct < 4; ++ct)
          acc[rt][ct] = __builtin_amdgcn_mfma_f32_16x16x32_bf16(
              af[rt], bfr[ct], acc[rt][ct], 0, 0, 0);
    }
    __builtin_amdgcn_s_setprio(0);
  };

  // T4 counted-vmcnt pipeline: loads for step t+1 stay in flight across
  // compute(t); each wave waits only for its 4 oldest (= step t's) loads.
  stage_a(0, 0);
  stage_b(0, 0);
  #pragma unroll
  for (int t = 0; t < NS; ++t){
    const int cur = t & 1;
    if (t + 1 < NS){
      stage_a(t+1, cur^1);
      stage_b(t+1, cur^1);
      asm volatile("s_waitcnt vmcnt(4)" ::: "memory");
    } else {
      asm volatile("s_waitcnt vmcnt(0)" ::: "memory");
    }
    __builtin_amdgcn_sched_barrier(0);
    __builtin_amdgcn_s_barrier();     // all waves' step-t data landed
    compute(cur);
    if (t + 1 < NS)
      __builtin_amdgcn_s_barrier();   // WAR: buffer cur free for step t+2
  }

  // C/D mapping (verified): col = l16, row = quad*4 + r
  #pragma unroll
  for (int ct = 0; ct < 4; ++ct){
    const int cout = wc + (ct<<4) + l16;
    #pragma unroll
    for (int rt = 0; rt < 2; ++rt){
      #pragma unroll
      for (int r = 0; r < 4; ++r){
        long row = rb + wr + (rt<<4) + (quad<<2) + r;
        if (row < (long)n_out){
          float v = acc[rt][ct][r] + bv[ct];
          if (RELU) v = v > 0.f ? v : 0.f;
          if constexpr (OUTMODE == 0 || OUTMODE == 2) outf[row*128 + cout] = v;
          if constexpr (OUTMODE == 1 || OUTMODE == 2) outb[row*128 + cout] = f2bf(v);
        }
      }
    }
  }
}

static inline long cdivl(long a, long b){ return (a + b - 1) / b; }

extern "C" void kernel_launch(void* const* d_in, const int* in_sizes, int n_in_args,
                              void* d_out, int out_size, void* d_ws, size_t ws_size,
                              hipStream_t stream) {
  const float* feats = (const float*)d_in[0];
  const float* w_c0 = (const float*)d_in[1];
  const float* b_c0 = (const float*)d_in[2];
  const int* in_c0  = (const int*)d_in[3];
  const int* out_c0 = (const int*)d_in[4];
  const float* w_d0 = (const float*)d_in[5];
  const float* b_d0 = (const float*)d_in[6];
  const int* in_d0  = (const int*)d_in[7];
  const int* out_d0 = (const int*)d_in[8];
  const float* w_c1 = (const float*)d_in[9];
  const float* b_c1 = (const float*)d_in[10];
  const int* in_c1  = (const int*)d_in[11];
  const int* out_c1 = (const int*)d_in[12];
  const float* w_d1 = (const float*)d_in[13];
  const float* b_d1 = (const float*)d_in[14];
  const int* in_d1  = (const int*)d_in[15];
  const int* out_d1 = (const int*)d_in[16];
  const float* w_c2 = (const float*)d_in[17];
  const float* b_c2 = (const float*)d_in[18];
  const int* in_c2  = (const int*)d_in[19];
  const int* out_c2 = (const int*)d_in[20];
  const float* w_d2 = (const float*)d_in[21];
  const float* b_d2 = (const float*)d_in[22];
  const int* in_d2  = (const int*)d_in[23];
  const int* out_d2 = (const int*)d_in[24];

  const int n0   = in_sizes[0];
  const int M_c0 = in_sizes[3]  / 9;
  const int M_d0 = in_sizes[7]  / 9;
  const int M_c1 = in_sizes[11] / 9;
  const int M_d1 = in_sizes[15] / 9;
  const int M_c2 = in_sizes[19] / 9;
  const int M_d2 = in_sizes[23] / 9;
  const int n1   = M_c1;
  const int n2   = M_c2;
  const int n3   = out_size/128 - n1 - n2;

  bool sane = n0 > 0 && out_size % 128 == 0 &&
              M_c0 > 0 && M_d0 > 0 && M_d1 > 0 && M_d2 > 0 &&
              n1 > 0 && n2 > 0 && n3 > 0;

  long maxElems = (long)n0*64;
  if ((long)n1*128 > maxElems) maxElems = (long)n1*128;
  if ((long)n2*128 > maxElems) maxElems = (long)n2*128;
  long fbytes = (maxElems*2 + 255)/256*256;
  long ntab   = sane ? 9L*((long)n0 + 2L*n1 + 2L*n2 + n3) : 0;
  long tbytes = (ntab*4 + 255)/256*256;
  long wt64  = 9L*128*64, wt128 = 9L*128*128;
  long wbytes = ((wt64 + 4*wt128)*2 + 255)/256*256;
  long zbytes = 256;
  long b1bytes = sane ? ((long)n2*128*2 + 255)/256*256 : 0;
  long b0bytes = sane ? ((long)n1*128*2 + 255)/256*256 : 0;
  long need_full = fbytes + tbytes + wbytes + zbytes + 256 + b1bytes + b0bytes;

  if (!sane || ws_size < (size_t)need_full){
    float C = (float)(16 + (int)std::min<size_t>(ws_size >> 20, (size_t)100000));
    if (!sane) C *= 1099511627776.0f;
    diag_kernel<<<cdivl(out_size,256),256,0,stream>>>((float*)d_out, out_size, C);
    return;
  }

  // ws: [ fbuf | tables x6 | wtb x5 | zero page | bf1 | bf0 ]
  uint16_t* fbuf = (uint16_t*)d_ws;
  long tab_off    = fbytes;
  long wtb_off    = fbytes + tbytes;
  long zp_off     = fbytes + tbytes + wbytes;
  long bf1_off    = zp_off + zbytes + 256;
  long bf0_off    = bf1_off + b1bytes;
  const char* wsb = (const char*)d_ws;
  int* tb        = (int*)((char*)d_ws + tab_off);
  float* zp_p    = (float*)((char*)d_ws + zp_off);
  uint16_t* bf1  = (uint16_t*)((char*)d_ws + bf1_off);
  uint16_t* bf0  = (uint16_t*)((char*)d_ws + bf0_off);

  // table int offsets (contiguous, order: c0 d0 c1 d1 c2 d2)
  long t_c0 = 0;
  long t_d0 = t_c0 + 9L*n0;
  long t_c1 = t_d0 + 9L*n1;
  long t_d1 = t_c1 + 9L*n1;
  long t_c2 = t_d1 + 9L*n2;
  long t_d2 = t_c2 + 9L*n2;

  float* out2 = (float*)d_out;
  float* out1 = out2 + (long)n3*128;
  float* out0 = out1 + (long)n2*128;

  // 1) table init (-1 = 0xFF bytes) + zero page, via SDMA memset
  hipMemsetAsync(tb, 0xFF, (size_t)ntab*4, stream);
  hipMemsetAsync(zp_p, 0, 256, stream);

  // 2) fused weight transpose + inverse-table build
  PBArgs pa;
  pa.w[0]=w_d0; pa.w[1]=w_c1; pa.w[2]=w_d1; pa.w[3]=w_c2; pa.w[4]=w_d2;
  pa.wb = (uint16_t*)((char*)d_ws + wtb_off);
  pa.wtotal = wt64 + 4*wt128;
  pa.im[0]=in_c0;  pa.om[0]=out_c0; pa.M[0]=M_c0; pa.nin[0]=n0; pa.nout[0]=n0; pa.toff[0]=t_c0;
  pa.im[1]=in_d0;  pa.om[1]=out_d0; pa.M[1]=M_d0; pa.nin[1]=n0; pa.nout[1]=n1; pa.toff[1]=t_d0;
  pa.im[2]=in_c1;  pa.om[2]=out_c1; pa.M[2]=M_c1; pa.nin[2]=n1; pa.nout[2]=n1; pa.toff[2]=t_c1;
  pa.im[3]=in_d1;  pa.om[3]=out_d1; pa.M[3]=M_d1; pa.nin[3]=n1; pa.nout[3]=n2; pa.toff[3]=t_d1;
  pa.im[4]=in_c2;  pa.om[4]=out_c2; pa.M[4]=M_c2; pa.nin[4]=n2; pa.nout[4]=n2; pa.toff[4]=t_c2;
  pa.im[5]=in_d2;  pa.om[5]=out_d2; pa.M[5]=M_d2; pa.nin[5]=n2; pa.nout[5]=n3; pa.toff[5]=t_d2;
  pa.bcum[0] = 0;
  for (int i = 0; i < 6; ++i) pa.bcum[i+1] = pa.bcum[i] + 9L*pa.M[i];
  pa.tb = tb;
  pa.total = pa.wtotal + pa.bcum[6];
  long pbg = std::min(cdivl(pa.total, 256), (long)4096);
  prep_build_kernel<<<(unsigned)pbg,256,0,stream>>>(pa);

  // 3) c0: feats fp32 -> fbuf(x) bf16 [n0][64]
  c0_tab_kernel<<<cdivl(n0,256),256,0,stream>>>(feats, w_c0, b_c0, tb + t_c0, fbuf, n0);

  // 4) d0: x bf16 -> out0 fp32 + bf0 bf16, relu
  mconv2_kernel<64,2,true><<<cdivl(n1,128),512,0,stream>>>(
      wsb, 0L, wtb_off, zp_off, b_d0, tb + t_d0, out0, bf0, n1);

  // 5) c1: bf0 bf16 -> fbuf(y) bf16
  mconv2_kernel<128,1,false><<<cdivl(n1,128),512,0,stream>>>(
      wsb, bf0_off, wtb_off + wt64*2, zp_off, b_c1, tb + t_c1, nullptr, fbuf, n1);

  // 6) d1: y bf16 -> out1 fp32 + bf1 bf16, relu
  mconv2_kernel<128,2,true><<<cdivl(n2,128),512,0,stream>>>(
      wsb, 0L, wtb_off + (wt64 + wt128)*2, zp_off, b_d1, tb + t_d1, out1, bf1, n2);

  // 7) c2: bf1 bf16 -> fbuf(z) bf16
  mconv2_kernel<128,1,false><<<cdivl(n2,128),512,0,stream>>>(
      wsb, bf1_off, wtb_off + (wt64 + 2*wt128)*2, zp_off, b_c2, tb + t_c2, nullptr, fbuf, n2);

  // 8) d2: z bf16 -> out2 fp32
  mconv2_kernel<128,0,false><<<cdivl(n3,128),512,0,stream>>>(
      wsb, 0L, wtb_off + (wt64 + 3*wt128)*2, zp_off, b_d2, tb + t_d2, out2, nullptr, n3);
}

// Round 10
// 490.801 us; speedup vs baseline: 2.8925x; 1.0255x over previous
//
#include <hip/hip_runtime.h>
#include <stdint.h>
#include <algorithm>

// Sparse conv encoder on MI355X. R15: verbatim restore of the R8 structure
// (487us measured session best). Probe ledger since: BK=32 deep pipeline
// -11% (barrier-bound); asymmetric A-depth-2 null (latency already covered);
// persistent mega-kernel -3x (per-block fence L2-flush amplification,
// FETCH/WRITE x5), acquire-removal null, elected-fence crash; memset+fused
// consolidation -3%. Conclusion: mconv plateau is gather-latency/service +
// ragged-tail structural; this round locks the measured optimum.
// Structure: flattened-K gather GEMM (K=9*CIN, BK=64), BM=128xBN=128,
// 512 thr (8 waves 4x2, wave 32x64), 2 LDS bufs A+B (64KB -> 2 blocks/CU),
// global_load_lds 16B, source-side XOR seg swizzle (0 bank conflicts),
// reg-precomputed gather offsets w/ zero-page fold, counted s_waitcnt
// vmcnt(4) + sched_barrier(0), setprio around MFMA, bijective XCD chunk
// swizzle, consolidated prep (9 dispatches).
// Predict: total 485-495us; mconv LDS ~65.5KB, VGPR ~88, conflicts 0.

#define DI __device__ __forceinline__

typedef __attribute__((ext_vector_type(8))) short bf16x8;
typedef __attribute__((ext_vector_type(4))) float f32x4;

DI uint16_t f2bf(float x){
  union{float f;uint32_t i;}v; v.f=x;
  uint32_t r = v.i + 0x7fffu + ((v.i>>16)&1u);
  return (uint16_t)(r>>16);
}
DI uint32_t pack2(float a, float b){
  return (uint32_t)f2bf(a) | ((uint32_t)f2bf(b) << 16);
}
DI void gload16(const void* g, void* l){
  __builtin_amdgcn_global_load_lds(
      (const __attribute__((address_space(1))) void*)g,
      (__attribute__((address_space(3))) void*)l, 16, 0, 0);
}

__global__ __launch_bounds__(256) void diag_kernel(float* __restrict__ out, long n, float c){
  long i = (long)blockIdx.x*256 + threadIdx.x;
  if (i < n) out[i] = c;
}

// fill all tables with -1 + zero the 256B zero page, one dispatch
__global__ __launch_bounds__(256) void init_all_kernel(
    int* __restrict__ tab, long ntab, float* __restrict__ zp){
  long i = (long)blockIdx.x*256 + threadIdx.x;
  if (i < ntab) tab[i] = -1;
  if (blockIdx.x == 0 && threadIdx.x < 64) zp[threadIdx.x] = 0.f;
}

struct BuildArgs {
  const int* im[6];
  const int* om[6];
  int   M[6];
  int   nin[6];
  int   nout[6];
  long  toff[6];   // int offsets into table base
};

// all 6 layers' inverse tables, one dispatch (z = layer, y = offset k)
__global__ __launch_bounds__(256) void build_all_kernel(
    BuildArgs a, int* __restrict__ tb){
  const int L = blockIdx.z, k = blockIdx.y;
  const int M = a.M[L];
  long t = (long)blockIdx.x*256 + threadIdx.x;
  if (t >= M) return;
  int ii = a.im[L][(long)k*M + t];
  int oo = a.om[L][(long)k*M + t];
  if (ii >= 0 && ii < a.nin[L] && oo >= 0 && oo < a.nout[L])
    tb[a.toff[L] + (long)k*a.nout[L] + oo] = ii;
}

// all 5 weight transposes (9,cin,128) fp32 -> (9,128,cin) bf16, one dispatch.
__global__ __launch_bounds__(256) void prep_all_kernel(
    const float* __restrict__ w0, const float* __restrict__ w1,
    const float* __restrict__ w2, const float* __restrict__ w3,
    const float* __restrict__ w4, uint16_t* __restrict__ wb, long total){
  const long wt64 = 9L*128*64, wt128 = 9L*128*128;
  long idx = (long)blockIdx.x*256 + threadIdx.x;
  if (idx >= total) return;
  int L; long r; int cin;
  if (idx < wt64){ L = 0; r = idx; cin = 64; }
  else { long j = idx - wt64; L = 1 + (int)(j / wt128); r = j % wt128; cin = 128; }
  const float* w = (L==0) ? w0 : (L==1) ? w1 : (L==2) ? w2 : (L==3) ? w3 : w4;
  int k = (int)(r / (128*cin));
  int rem = (int)(r % (128*cin));
  int cout = rem / cin, ci = rem % cin;
  wb[idx] = f2bf(w[((long)k*cin + ci)*128 + cout]);
}

// c0 (1->64 ch) via table: thread = row; 9 table reads + 9 cached gathers + FMA.
__global__ __launch_bounds__(256) void c0_tab_kernel(
    const float* __restrict__ feats, const float* __restrict__ w,
    const float* __restrict__ bias, const int* __restrict__ tab,
    uint16_t* __restrict__ out, int n_out){
  __shared__ float w_s[576];
  __shared__ float b_s[64];
  const int tid = threadIdx.x;
  for (int i = tid; i < 576; i += 256) w_s[i] = w[i];
  if (tid < 64) b_s[tid] = bias[tid];
  __syncthreads();
  long r = (long)blockIdx.x*256 + tid;
  if (r >= n_out) return;
  float f[9];
  #pragma unroll
  for (int k = 0; k < 9; k++){
    int gi = tab[(long)k*n_out + r];
    f[k] = (gi >= 0) ? feats[gi] : 0.f;
  }
  uint16_t* dst = out + r*64;
  #pragma unroll
  for (int c0 = 0; c0 < 64; c0 += 16){
    float a[16];
    #pragma unroll
    for (int j = 0; j < 16; j++) a[j] = b_s[c0+j];
    #pragma unroll
    for (int k = 0; k < 9; k++){
      float fk = f[k];
      #pragma unroll
      for (int j = 0; j < 16; j++) a[j] += fk * w_s[k*64 + c0 + j];
    }
    uint4 o0, o1;
    o0.x = pack2(a[0],a[1]);   o0.y = pack2(a[2],a[3]);
    o0.z = pack2(a[4],a[5]);   o0.w = pack2(a[6],a[7]);
    o1.x = pack2(a[8],a[9]);   o1.y = pack2(a[10],a[11]);
    o1.z = pack2(a[12],a[13]); o1.w = pack2(a[14],a[15]);
    *(uint4*)(dst + c0)     = o0;
    *(uint4*)(dst + c0 + 8) = o1;
  }
}

// Flattened-K gathered GEMM, BM=128 x BN=128, BK=64, 512 thr (8 waves 4x2,
// wave tile 32x64), 2 blocks/CU. T4 counted-vmcnt pipeline (R8-proven).
// Input always bf16 [n_in][CIN] inside ws at in_off.
// OUTMODE: 0 = fp32 only; 1 = bf16 only; 2 = both.
template<int CIN, int OUTMODE, bool RELU>
__global__ __launch_bounds__(512,4) void mconv2_kernel(
    const char* __restrict__ ws_base, long in_off, long wtb_off, long zp_off,
    const float* __restrict__ bias, const int* __restrict__ tab,
    float* __restrict__ outf, uint16_t* __restrict__ outb, int n_out){
  constexpr int NS = 9*CIN/64;                       // K-steps of 64
  __shared__ __align__(16) uint16_t ab[2][128*64];   // A: 128 rows x BK
  __shared__ __align__(16) uint16_t bb[2][128*64];   // B: 128 couts x BK

  const int tid = threadIdx.x;
  // bijective XCD-chunked swizzle (m204) for gather L2 locality
  const int nwg = gridDim.x, orig = blockIdx.x;
  const int q = nwg >> 3, rr = nwg & 7, xcd = orig & 7, pos = orig >> 3;
  const int wg = (xcd < rr ? xcd*(q+1) : rr*(q+1) + (xcd-rr)*q) + pos;
  const long rb = (long)wg * 128;

  const int r0 = tid >> 3, sg = tid & 7;
  const int ss0 = sg ^ (r0 & 7);       // r1=r0+64 -> same &7 -> same swizzle

  // A gather offsets: ws-relative uint32, zero-page select folded.
  uint32_t offA[2][9];
  #pragma unroll
  for (int kk = 0; kk < 9; ++kk){
    #pragma unroll
    for (int it = 0; it < 2; ++it){
      long row = rb + it*64 + r0;
      int gi = (row < (long)n_out) ? tab[(long)kk*n_out + row] : -1;
      offA[it][kk] = (gi >= 0)
          ? (uint32_t)(in_off + (long)gi*(CIN*2) + ss0*16)
          : (uint32_t)(zp_off + ss0*16);
    }
  }
  const uint32_t offB = (uint32_t)(wtb_off + ((long)r0*CIN + ss0*8)*2);

  const int lane = tid & 63;
  const int wv = tid >> 6;
  const int wr = (wv >> 1) << 5;    // 4 row-waves x 32
  const int wc = (wv & 1) << 6;     // 2 col-waves x 64
  const int l16 = lane & 15, quad = lane >> 4;

  // preload bias so the K-loop has exactly 4 VMEM instrs/wave/step
  float bv[4];
  #pragma unroll
  for (int ct = 0; ct < 4; ++ct) bv[ct] = bias[wc + (ct<<4) + l16];

  f32x4 acc[2][4];
  #pragma unroll
  for (int i = 0; i < 2; i++)
    #pragma unroll
    for (int j = 0; j < 4; j++)
      acc[i][j] = (f32x4){0.f,0.f,0.f,0.f};

  auto stage_a = [&](int step, int nb){
    const int kk  = (CIN == 64) ? step : (step >> 1);
    const int c0b = (CIN == 64) ? 0 : ((step & 1) * 128);
    #pragma unroll
    for (int it = 0; it < 2; ++it)
      gload16(ws_base + offA[it][kk] + c0b, &ab[nb][(it*512+tid)*8]);
  };
  auto stage_b = [&](int step, int nb){
    const int kk  = (CIN == 64) ? step : (step >> 1);
    const int c0b = (CIN == 64) ? 0 : ((step & 1) * 128);
    const uint32_t base = offB + (uint32_t)((long)kk*128*CIN*2 + c0b);
    #pragma unroll
    for (int it = 0; it < 2; ++it)
      gload16(ws_base + base + it*(64*CIN*2), &bb[nb][(it*512+tid)*8]);
  };
  auto compute = [&](int nb){
    const uint16_t* A  = &ab[nb][0];
    const uint16_t* Bm = &bb[nb][0];
    __builtin_amdgcn_s_setprio(1);
    #pragma unroll
    for (int ch = 0; ch < 2; ++ch){
      // row&7 == l16&7 for every fragment row (wr,wc,u*16 are 0 mod 8)
      const int xs = ((((ch << 2) + quad) ^ (l16 & 7)) << 3);
      bf16x8 af[2], bfr[4];
      #pragma unroll
      for (int u = 0; u < 2; ++u)
        af[u]  = *(const bf16x8*)&A [((wr + (u<<4) + l16) << 6) + xs];
      #pragma unroll
      for (int u = 0; u < 4; ++u)
        bfr[u] = *(const bf16x8*)&Bm[((wc + (u<<4) + l16) << 6) + xs];
      #pragma unroll
      for (int rt = 0; rt < 2; ++rt)
        #pragma unroll
        for (int ct = 0; ct < 4; ++ct)
          acc[rt][ct] = __builtin_amdgcn_mfma_f32_16x16x32_bf16(
              af[rt], bfr[ct], acc[rt][ct], 0, 0, 0);
    }
    __builtin_amdgcn_s_setprio(0);
  };

  // T4 counted-vmcnt pipeline: loads for step t+1 stay in flight across
  // compute(t); each wave waits only for its 4 oldest (= step t's) loads.
  stage_a(0, 0);
  stage_b(0, 0);
  #pragma unroll
  for (int t = 0; t < NS; ++t){
    const int cur = t & 1;
    if (t + 1 < NS){
      stage_a(t+1, cur^1);
      stage_b(t+1, cur^1);
      asm volatile("s_waitcnt vmcnt(4)" ::: "memory");
    } else {
      asm volatile("s_waitcnt vmcnt(0)" ::: "memory");
    }
    __builtin_amdgcn_sched_barrier(0);
    __builtin_amdgcn_s_barrier();     // all waves' step-t data landed
    compute(cur);
    if (t + 1 < NS)
      __builtin_amdgcn_s_barrier();   // WAR: buffer cur free for step t+2
  }

  // C/D mapping (verified): col = l16, row = quad*4 + r
  #pragma unroll
  for (int ct = 0; ct < 4; ++ct){
    const int cout = wc + (ct<<4) + l16;
    #pragma unroll
    for (int rt = 0; rt < 2; ++rt){
      #pragma unroll
      for (int r = 0; r < 4; ++r){
        long row = rb + wr + (rt<<4) + (quad<<2) + r;
        if (row < (long)n_out){
          float v = acc[rt][ct][r] + bv[ct];
          if (RELU) v = v > 0.f ? v : 0.f;
          if constexpr (OUTMODE == 0 || OUTMODE == 2) outf[row*128 + cout] = v;
          if constexpr (OUTMODE == 1 || OUTMODE == 2) outb[row*128 + cout] = f2bf(v);
        }
      }
    }
  }
}

static inline long cdivl(long a, long b){ return (a + b - 1) / b; }

extern "C" void kernel_launch(void* const* d_in, const int* in_sizes, int n_in_args,
                              void* d_out, int out_size, void* d_ws, size_t ws_size,
                              hipStream_t stream) {
  const float* feats = (const float*)d_in[0];
  const float* w_c0 = (const float*)d_in[1];
  const float* b_c0 = (const float*)d_in[2];
  const int* in_c0  = (const int*)d_in[3];
  const int* out_c0 = (const int*)d_in[4];
  const float* w_d0 = (const float*)d_in[5];
  const float* b_d0 = (const float*)d_in[6];
  const int* in_d0  = (const int*)d_in[7];
  const int* out_d0 = (const int*)d_in[8];
  const float* w_c1 = (const float*)d_in[9];
  const float* b_c1 = (const float*)d_in[10];
  const int* in_c1  = (const int*)d_in[11];
  const int* out_c1 = (const int*)d_in[12];
  const float* w_d1 = (const float*)d_in[13];
  const float* b_d1 = (const float*)d_in[14];
  const int* in_d1  = (const int*)d_in[15];
  const int* out_d1 = (const int*)d_in[16];
  const float* w_c2 = (const float*)d_in[17];
  const float* b_c2 = (const float*)d_in[18];
  const int* in_c2  = (const int*)d_in[19];
  const int* out_c2 = (const int*)d_in[20];
  const float* w_d2 = (const float*)d_in[21];
  const float* b_d2 = (const float*)d_in[22];
  const int* in_d2  = (const int*)d_in[23];
  const int* out_d2 = (const int*)d_in[24];

  const int n0   = in_sizes[0];
  const int M_c0 = in_sizes[3]  / 9;
  const int M_d0 = in_sizes[7]  / 9;
  const int M_c1 = in_sizes[11] / 9;
  const int M_d1 = in_sizes[15] / 9;
  const int M_c2 = in_sizes[19] / 9;
  const int M_d2 = in_sizes[23] / 9;
  const int n1   = M_c1;
  const int n2   = M_c2;
  const int n3   = out_size/128 - n1 - n2;

  bool sane = n0 > 0 && out_size % 128 == 0 &&
              M_c0 > 0 && M_d0 > 0 && M_d1 > 0 && M_d2 > 0 &&
              n1 > 0 && n2 > 0 && n3 > 0;

  long maxElems = (long)n0*64;
  if ((long)n1*128 > maxElems) maxElems = (long)n1*128;
  if ((long)n2*128 > maxElems) maxElems = (long)n2*128;
  long fbytes = (maxElems*2 + 255)/256*256;
  long ntab   = sane ? 9L*((long)n0 + 2L*n1 + 2L*n2 + n3) : 0;
  long tbytes = (ntab*4 + 255)/256*256;
  long wt64  = 9L*128*64, wt128 = 9L*128*128;
  long wbytes = ((wt64 + 4*wt128)*2 + 255)/256*256;
  long zbytes = 256;
  long b1bytes = sane ? ((long)n2*128*2 + 255)/256*256 : 0;
  long b0bytes = sane ? ((long)n1*128*2 + 255)/256*256 : 0;
  long need_full = fbytes + tbytes + wbytes + zbytes + 256 + b1bytes + b0bytes;

  if (!sane || ws_size < (size_t)need_full){
    float C = (float)(16 + (int)std::min<size_t>(ws_size >> 20, (size_t)100000));
    if (!sane) C *= 1099511627776.0f;
    diag_kernel<<<cdivl(out_size,256),256,0,stream>>>((float*)d_out, out_size, C);
    return;
  }

  // ws: [ fbuf | tables x6 | wtb x5 | zero page | bf1 | bf0 ]
  uint16_t* fbuf = (uint16_t*)d_ws;
  long tab_off    = fbytes;
  long wtb_off    = fbytes + tbytes;
  long zp_off     = fbytes + tbytes + wbytes;
  long bf1_off    = zp_off + zbytes + 256;
  long bf0_off    = bf1_off + b1bytes;
  const char* wsb = (const char*)d_ws;
  int* tb        = (int*)((char*)d_ws + tab_off);
  float* zp_p    = (float*)((char*)d_ws + zp_off);
  uint16_t* bf1  = (uint16_t*)((char*)d_ws + bf1_off);
  uint16_t* bf0  = (uint16_t*)((char*)d_ws + bf0_off);

  // table int offsets (contiguous, order: c0 d0 c1 d1 c2 d2)
  long t_c0 = 0;
  long t_d0 = t_c0 + 9L*n0;
  long t_c1 = t_d0 + 9L*n1;
  long t_d1 = t_c1 + 9L*n1;
  long t_c2 = t_d1 + 9L*n2;
  long t_d2 = t_c2 + 9L*n2;

  float* out2 = (float*)d_out;
  float* out1 = out2 + (long)n3*128;
  float* out0 = out1 + (long)n2*128;

  // 1) init all tables + zero page
  init_all_kernel<<<cdivl(ntab,256),256,0,stream>>>(tb, ntab, zp_p);

  // 2) build all 6 tables
  BuildArgs ba;
  ba.im[0]=in_c0;  ba.om[0]=out_c0; ba.M[0]=M_c0; ba.nin[0]=n0; ba.nout[0]=n0; ba.toff[0]=t_c0;
  ba.im[1]=in_d0;  ba.om[1]=out_d0; ba.M[1]=M_d0; ba.nin[1]=n0; ba.nout[1]=n1; ba.toff[1]=t_d0;
  ba.im[2]=in_c1;  ba.om[2]=out_c1; ba.M[2]=M_c1; ba.nin[2]=n1; ba.nout[2]=n1; ba.toff[2]=t_c1;
  ba.im[3]=in_d1;  ba.om[3]=out_d1; ba.M[3]=M_d1; ba.nin[3]=n1; ba.nout[3]=n2; ba.toff[3]=t_d1;
  ba.im[4]=in_c2;  ba.om[4]=out_c2; ba.M[4]=M_c2; ba.nin[4]=n2; ba.nout[4]=n2; ba.toff[4]=t_c2;
  ba.im[5]=in_d2;  ba.om[5]=out_d2; ba.M[5]=M_d2; ba.nin[5]=n2; ba.nout[5]=n3; ba.toff[5]=t_d2;
  long maxM = M_c0;
  for (int i = 0; i < 6; ++i) if (ba.M[i] > maxM) maxM = ba.M[i];
  dim3 bg((unsigned)cdivl(maxM,256), 9, 6);
  build_all_kernel<<<bg,256,0,stream>>>(ba, tb);

  // 3) all weight transposes
  long wtotal = wt64 + 4*wt128;
  prep_all_kernel<<<cdivl(wtotal,256),256,0,stream>>>(
      w_d0, w_c1, w_d1, w_c2, w_d2,
      (uint16_t*)((char*)d_ws + wtb_off), wtotal);

  // 4) c0: feats fp32 -> fbuf(x) bf16 [n0][64]
  c0_tab_kernel<<<cdivl(n0,256),256,0,stream>>>(feats, w_c0, b_c0, tb + t_c0, fbuf, n0);

  // 5) d0: x bf16 -> out0 fp32 + bf0 bf16, relu
  mconv2_kernel<64,2,true><<<cdivl(n1,128),512,0,stream>>>(
      wsb, 0L, wtb_off, zp_off, b_d0, tb + t_d0, out0, bf0, n1);

  // 6) c1: bf0 bf16 -> fbuf(y) bf16
  mconv2_kernel<128,1,false><<<cdivl(n1,128),512,0,stream>>>(
      wsb, bf0_off, wtb_off + wt64*2, zp_off, b_c1, tb + t_c1, nullptr, fbuf, n1);

  // 7) d1: y bf16 -> out1 fp32 + bf1 bf16, relu
  mconv2_kernel<128,2,true><<<cdivl(n2,128),512,0,stream>>>(
      wsb, 0L, wtb_off + (wt64 + wt128)*2, zp_off, b_d1, tb + t_d1, out1, bf1, n2);

  // 8) c2: bf1 bf16 -> fbuf(z) bf16
  mconv2_kernel<128,1,false><<<cdivl(n2,128),512,0,stream>>>(
      wsb, bf1_off, wtb_off + (wt64 + 2*wt128)*2, zp_off, b_c2, tb + t_c2, nullptr, fbuf, n2);

  // 9) d2: z bf16 -> out2 fp32
  mconv2_kernel<128,0,false><<<cdivl(n3,128),512,0,stream>>>(
      wsb, 0L, wtb_off + (wt64 + 3*wt128)*2, zp_off, b_d2, tb + t_d2, out2, nullptr, n3);
}

// Round 11
// 480.815 us; speedup vs baseline: 2.9525x; 1.0208x over previous
//
#include <hip/hip_runtime.h>
#include <stdint.h>
#include <algorithm>

// Sparse conv encoder on MI355X. R16: R15 (490.8us, reproduced plateau
// 487-491) + two catalog-backed micro-levers:
//  (a) REMOVE s_setprio around MFMA: T5 is null-to-negative on
//      barrier-lockstep GEMM (m190: -14TF). Our mconv is lockstep (8 waves
//      barrier every K-step, both co-resident blocks same schedule); the
//      prio-boosted MFMA wave can starve the sibling block's staging issue.
//  (b) Fuse init_all+prep_all (independent: transposes don't touch tables):
//      9 -> 8 dispatches (-5.1us measured per-gap).
// Everything else byte-identical to the 487us-proven structure: flattened-K
// gather GEMM (K=9*CIN, BK=64), BM=128xBN=128, 512 thr (8 waves 4x2, wave
// 32x64), 2 LDS bufs A+B (64KB -> 2 blocks/CU), global_load_lds 16B,
// source-side XOR seg swizzle (0 bank conflicts), reg-precomputed gather
// offsets w/ zero-page fold, counted s_waitcnt vmcnt(4) + sched_barrier(0),
// bijective XCD chunk swizzle.
// Predict: 478-488us. If >=487: both levers null -> declare practical floor.

#define DI __device__ __forceinline__

typedef __attribute__((ext_vector_type(8))) short bf16x8;
typedef __attribute__((ext_vector_type(4))) float f32x4;

DI uint16_t f2bf(float x){
  union{float f;uint32_t i;}v; v.f=x;
  uint32_t r = v.i + 0x7fffu + ((v.i>>16)&1u);
  return (uint16_t)(r>>16);
}
DI uint32_t pack2(float a, float b){
  return (uint32_t)f2bf(a) | ((uint32_t)f2bf(b) << 16);
}
DI void gload16(const void* g, void* l){
  __builtin_amdgcn_global_load_lds(
      (const __attribute__((address_space(1))) void*)g,
      (__attribute__((address_space(3))) void*)l, 16, 0, 0);
}

__global__ __launch_bounds__(256) void diag_kernel(float* __restrict__ out, long n, float c){
  long i = (long)blockIdx.x*256 + threadIdx.x;
  if (i < n) out[i] = c;
}

// Fused: tables=-1 + zero page (items [0,ntab]) and the 5 weight transposes
// (items [ntab, ntab+wtotal)). Independent work, one dispatch.
__global__ __launch_bounds__(256) void init_prep_kernel(
    int* __restrict__ tab, long ntab, float* __restrict__ zp,
    const float* __restrict__ w0, const float* __restrict__ w1,
    const float* __restrict__ w2, const float* __restrict__ w3,
    const float* __restrict__ w4, uint16_t* __restrict__ wb, long wtotal){
  const long wt64 = 9L*128*64, wt128 = 9L*128*128;
  long i = (long)blockIdx.x*256 + threadIdx.x;
  if (blockIdx.x == 0 && threadIdx.x < 64) zp[threadIdx.x] = 0.f;
  if (i < ntab){
    tab[i] = -1;
  } else if (i < ntab + wtotal){
    long idx = i - ntab;
    int L; long r; int cin;
    if (idx < wt64){ L = 0; r = idx; cin = 64; }
    else { long j = idx - wt64; L = 1 + (int)(j / wt128); r = j % wt128; cin = 128; }
    const float* w = (L==0) ? w0 : (L==1) ? w1 : (L==2) ? w2 : (L==3) ? w3 : w4;
    int k = (int)(r / (128*cin));
    int rem = (int)(r % (128*cin));
    int cout = rem / cin, ci = rem % cin;
    wb[idx] = f2bf(w[((long)k*cin + ci)*128 + cout]);
  }
}

struct BuildArgs {
  const int* im[6];
  const int* om[6];
  int   M[6];
  int   nin[6];
  int   nout[6];
  long  toff[6];   // int offsets into table base
};

// all 6 layers' inverse tables, one dispatch (z = layer, y = offset k)
__global__ __launch_bounds__(256) void build_all_kernel(
    BuildArgs a, int* __restrict__ tb){
  const int L = blockIdx.z, k = blockIdx.y;
  const int M = a.M[L];
  long t = (long)blockIdx.x*256 + threadIdx.x;
  if (t >= M) return;
  int ii = a.im[L][(long)k*M + t];
  int oo = a.om[L][(long)k*M + t];
  if (ii >= 0 && ii < a.nin[L] && oo >= 0 && oo < a.nout[L])
    tb[a.toff[L] + (long)k*a.nout[L] + oo] = ii;
}

// c0 (1->64 ch) via table: thread = row; 9 table reads + 9 cached gathers + FMA.
__global__ __launch_bounds__(256) void c0_tab_kernel(
    const float* __restrict__ feats, const float* __restrict__ w,
    const float* __restrict__ bias, const int* __restrict__ tab,
    uint16_t* __restrict__ out, int n_out){
  __shared__ float w_s[576];
  __shared__ float b_s[64];
  const int tid = threadIdx.x;
  for (int i = tid; i < 576; i += 256) w_s[i] = w[i];
  if (tid < 64) b_s[tid] = bias[tid];
  __syncthreads();
  long r = (long)blockIdx.x*256 + tid;
  if (r >= n_out) return;
  float f[9];
  #pragma unroll
  for (int k = 0; k < 9; k++){
    int gi = tab[(long)k*n_out + r];
    f[k] = (gi >= 0) ? feats[gi] : 0.f;
  }
  uint16_t* dst = out + r*64;
  #pragma unroll
  for (int c0 = 0; c0 < 64; c0 += 16){
    float a[16];
    #pragma unroll
    for (int j = 0; j < 16; j++) a[j] = b_s[c0+j];
    #pragma unroll
    for (int k = 0; k < 9; k++){
      float fk = f[k];
      #pragma unroll
      for (int j = 0; j < 16; j++) a[j] += fk * w_s[k*64 + c0 + j];
    }
    uint4 o0, o1;
    o0.x = pack2(a[0],a[1]);   o0.y = pack2(a[2],a[3]);
    o0.z = pack2(a[4],a[5]);   o0.w = pack2(a[6],a[7]);
    o1.x = pack2(a[8],a[9]);   o1.y = pack2(a[10],a[11]);
    o1.z = pack2(a[12],a[13]); o1.w = pack2(a[14],a[15]);
    *(uint4*)(dst + c0)     = o0;
    *(uint4*)(dst + c0 + 8) = o1;
  }
}

// Flattened-K gathered GEMM, BM=128 x BN=128, BK=64, 512 thr (8 waves 4x2,
// wave tile 32x64), 2 blocks/CU. T4 counted-vmcnt pipeline (R8-proven).
// Input always bf16 [n_in][CIN] inside ws at in_off.
// OUTMODE: 0 = fp32 only; 1 = bf16 only; 2 = both.
template<int CIN, int OUTMODE, bool RELU>
__global__ __launch_bounds__(512,4) void mconv2_kernel(
    const char* __restrict__ ws_base, long in_off, long wtb_off, long zp_off,
    const float* __restrict__ bias, const int* __restrict__ tab,
    float* __restrict__ outf, uint16_t* __restrict__ outb, int n_out){
  constexpr int NS = 9*CIN/64;                       // K-steps of 64
  __shared__ __align__(16) uint16_t ab[2][128*64];   // A: 128 rows x BK
  __shared__ __align__(16) uint16_t bb[2][128*64];   // B: 128 couts x BK

  const int tid = threadIdx.x;
  // bijective XCD-chunked swizzle (m204) for gather L2 locality
  const int nwg = gridDim.x, orig = blockIdx.x;
  const int q = nwg >> 3, rr = nwg & 7, xcd = orig & 7, pos = orig >> 3;
  const int wg = (xcd < rr ? xcd*(q+1) : rr*(q+1) + (xcd-rr)*q) + pos;
  const long rb = (long)wg * 128;

  const int r0 = tid >> 3, sg = tid & 7;
  const int ss0 = sg ^ (r0 & 7);       // r1=r0+64 -> same &7 -> same swizzle

  // A gather offsets: ws-relative uint32, zero-page select folded.
  uint32_t offA[2][9];
  #pragma unroll
  for (int kk = 0; kk < 9; ++kk){
    #pragma unroll
    for (int it = 0; it < 2; ++it){
      long row = rb + it*64 + r0;
      int gi = (row < (long)n_out) ? tab[(long)kk*n_out + row] : -1;
      offA[it][kk] = (gi >= 0)
          ? (uint32_t)(in_off + (long)gi*(CIN*2) + ss0*16)
          : (uint32_t)(zp_off + ss0*16);
    }
  }
  const uint32_t offB = (uint32_t)(wtb_off + ((long)r0*CIN + ss0*8)*2);

  const int lane = tid & 63;
  const int wv = tid >> 6;
  const int wr = (wv >> 1) << 5;    // 4 row-waves x 32
  const int wc = (wv & 1) << 6;     // 2 col-waves x 64
  const int l16 = lane & 15, quad = lane >> 4;

  // preload bias so the K-loop has exactly 4 VMEM instrs/wave/step
  float bv[4];
  #pragma unroll
  for (int ct = 0; ct < 4; ++ct) bv[ct] = bias[wc + (ct<<4) + l16];

  f32x4 acc[2][4];
  #pragma unroll
  for (int i = 0; i < 2; i++)
    #pragma unroll
    for (int j = 0; j < 4; j++)
      acc[i][j] = (f32x4){0.f,0.f,0.f,0.f};

  auto stage_a = [&](int step, int nb){
    const int kk  = (CIN == 64) ? step : (step >> 1);
    const int c0b = (CIN == 64) ? 0 : ((step & 1) * 128);
    #pragma unroll
    for (int it = 0; it < 2; ++it)
      gload16(ws_base + offA[it][kk] + c0b, &ab[nb][(it*512+tid)*8]);
  };
  auto stage_b = [&](int step, int nb){
    const int kk  = (CIN == 64) ? step : (step >> 1);
    const int c0b = (CIN == 64) ? 0 : ((step & 1) * 128);
    const uint32_t base = offB + (uint32_t)((long)kk*128*CIN*2 + c0b);
    #pragma unroll
    for (int it = 0; it < 2; ++it)
      gload16(ws_base + base + it*(64*CIN*2), &bb[nb][(it*512+tid)*8]);
  };
  auto compute = [&](int nb){
    const uint16_t* A  = &ab[nb][0];
    const uint16_t* Bm = &bb[nb][0];
    // setprio removed (R16): T5 null-to-negative on lockstep schedules (m190)
    #pragma unroll
    for (int ch = 0; ch < 2; ++ch){
      // row&7 == l16&7 for every fragment row (wr,wc,u*16 are 0 mod 8)
      const int xs = ((((ch << 2) + quad) ^ (l16 & 7)) << 3);
      bf16x8 af[2], bfr[4];
      #pragma unroll
      for (int u = 0; u < 2; ++u)
        af[u]  = *(const bf16x8*)&A [((wr + (u<<4) + l16) << 6) + xs];
      #pragma unroll
      for (int u = 0; u < 4; ++u)
        bfr[u] = *(const bf16x8*)&Bm[((wc + (u<<4) + l16) << 6) + xs];
      #pragma unroll
      for (int rt = 0; rt < 2; ++rt)
        #pragma unroll
        for (int ct = 0; ct < 4; ++ct)
          acc[rt][ct] = __builtin_amdgcn_mfma_f32_16x16x32_bf16(
              af[rt], bfr[ct], acc[rt][ct], 0, 0, 0);
    }
  };

  // T4 counted-vmcnt pipeline: loads for step t+1 stay in flight across
  // compute(t); each wave waits only for its 4 oldest (= step t's) loads.
  stage_a(0, 0);
  stage_b(0, 0);
  #pragma unroll
  for (int t = 0; t < NS; ++t){
    const int cur = t & 1;
    if (t + 1 < NS){
      stage_a(t+1, cur^1);
      stage_b(t+1, cur^1);
      asm volatile("s_waitcnt vmcnt(4)" ::: "memory");
    } else {
      asm volatile("s_waitcnt vmcnt(0)" ::: "memory");
    }
    __builtin_amdgcn_sched_barrier(0);
    __builtin_amdgcn_s_barrier();     // all waves' step-t data landed
    compute(cur);
    if (t + 1 < NS)
      __builtin_amdgcn_s_barrier();   // WAR: buffer cur free for step t+2
  }

  // C/D mapping (verified): col = l16, row = quad*4 + r
  #pragma unroll
  for (int ct = 0; ct < 4; ++ct){
    const int cout = wc + (ct<<4) + l16;
    #pragma unroll
    for (int rt = 0; rt < 2; ++rt){
      #pragma unroll
      for (int r = 0; r < 4; ++r){
        long row = rb + wr + (rt<<4) + (quad<<2) + r;
        if (row < (long)n_out){
          float v = acc[rt][ct][r] + bv[ct];
          if (RELU) v = v > 0.f ? v : 0.f;
          if constexpr (OUTMODE == 0 || OUTMODE == 2) outf[row*128 + cout] = v;
          if constexpr (OUTMODE == 1 || OUTMODE == 2) outb[row*128 + cout] = f2bf(v);
        }
      }
    }
  }
}

static inline long cdivl(long a, long b){ return (a + b - 1) / b; }

extern "C" void kernel_launch(void* const* d_in, const int* in_sizes, int n_in_args,
                              void* d_out, int out_size, void* d_ws, size_t ws_size,
                              hipStream_t stream) {
  const float* feats = (const float*)d_in[0];
  const float* w_c0 = (const float*)d_in[1];
  const float* b_c0 = (const float*)d_in[2];
  const int* in_c0  = (const int*)d_in[3];
  const int* out_c0 = (const int*)d_in[4];
  const float* w_d0 = (const float*)d_in[5];
  const float* b_d0 = (const float*)d_in[6];
  const int* in_d0  = (const int*)d_in[7];
  const int* out_d0 = (const int*)d_in[8];
  const float* w_c1 = (const float*)d_in[9];
  const float* b_c1 = (const float*)d_in[10];
  const int* in_c1  = (const int*)d_in[11];
  const int* out_c1 = (const int*)d_in[12];
  const float* w_d1 = (const float*)d_in[13];
  const float* b_d1 = (const float*)d_in[14];
  const int* in_d1  = (const int*)d_in[15];
  const int* out_d1 = (const int*)d_in[16];
  const float* w_c2 = (const float*)d_in[17];
  const float* b_c2 = (const float*)d_in[18];
  const int* in_c2  = (const int*)d_in[19];
  const int* out_c2 = (const int*)d_in[20];
  const float* w_d2 = (const float*)d_in[21];
  const float* b_d2 = (const float*)d_in[22];
  const int* in_d2  = (const int*)d_in[23];
  const int* out_d2 = (const int*)d_in[24];

  const int n0   = in_sizes[0];
  const int M_c0 = in_sizes[3]  / 9;
  const int M_d0 = in_sizes[7]  / 9;
  const int M_c1 = in_sizes[11] / 9;
  const int M_d1 = in_sizes[15] / 9;
  const int M_c2 = in_sizes[19] / 9;
  const int M_d2 = in_sizes[23] / 9;
  const int n1   = M_c1;
  const int n2   = M_c2;
  const int n3   = out_size/128 - n1 - n2;

  bool sane = n0 > 0 && out_size % 128 == 0 &&
              M_c0 > 0 && M_d0 > 0 && M_d1 > 0 && M_d2 > 0 &&
              n1 > 0 && n2 > 0 && n3 > 0;

  long maxElems = (long)n0*64;
  if ((long)n1*128 > maxElems) maxElems = (long)n1*128;
  if ((long)n2*128 > maxElems) maxElems = (long)n2*128;
  long fbytes = (maxElems*2 + 255)/256*256;
  long ntab   = sane ? 9L*((long)n0 + 2L*n1 + 2L*n2 + n3) : 0;
  long tbytes = (ntab*4 + 255)/256*256;
  long wt64  = 9L*128*64, wt128 = 9L*128*128;
  long wbytes = ((wt64 + 4*wt128)*2 + 255)/256*256;
  long zbytes = 256;
  long b1bytes = sane ? ((long)n2*128*2 + 255)/256*256 : 0;
  long b0bytes = sane ? ((long)n1*128*2 + 255)/256*256 : 0;
  long need_full = fbytes + tbytes + wbytes + zbytes + 256 + b1bytes + b0bytes;

  if (!sane || ws_size < (size_t)need_full){
    float C = (float)(16 + (int)std::min<size_t>(ws_size >> 20, (size_t)100000));
    if (!sane) C *= 1099511627776.0f;
    diag_kernel<<<cdivl(out_size,256),256,0,stream>>>((float*)d_out, out_size, C);
    return;
  }

  // ws: [ fbuf | tables x6 | wtb x5 | zero page | bf1 | bf0 ]
  uint16_t* fbuf = (uint16_t*)d_ws;
  long tab_off    = fbytes;
  long wtb_off    = fbytes + tbytes;
  long zp_off     = fbytes + tbytes + wbytes;
  long bf1_off    = zp_off + zbytes + 256;
  long bf0_off    = bf1_off + b1bytes;
  const char* wsb = (const char*)d_ws;
  int* tb        = (int*)((char*)d_ws + tab_off);
  float* zp_p    = (float*)((char*)d_ws + zp_off);
  uint16_t* bf1  = (uint16_t*)((char*)d_ws + bf1_off);
  uint16_t* bf0  = (uint16_t*)((char*)d_ws + bf0_off);

  // table int offsets (contiguous, order: c0 d0 c1 d1 c2 d2)
  long t_c0 = 0;
  long t_d0 = t_c0 + 9L*n0;
  long t_c1 = t_d0 + 9L*n1;
  long t_d1 = t_c1 + 9L*n1;
  long t_c2 = t_d1 + 9L*n2;
  long t_d2 = t_c2 + 9L*n2;

  float* out2 = (float*)d_out;
  float* out1 = out2 + (long)n3*128;
  float* out0 = out1 + (long)n2*128;

  // 1) init tables + zero page + all weight transposes (fused, independent)
  long wtotal = wt64 + 4*wt128;
  init_prep_kernel<<<cdivl(ntab + wtotal,256),256,0,stream>>>(
      tb, ntab, zp_p, w_d0, w_c1, w_d1, w_c2, w_d2,
      (uint16_t*)((char*)d_ws + wtb_off), wtotal);

  // 2) build all 6 tables
  BuildArgs ba;
  ba.im[0]=in_c0;  ba.om[0]=out_c0; ba.M[0]=M_c0; ba.nin[0]=n0; ba.nout[0]=n0; ba.toff[0]=t_c0;
  ba.im[1]=in_d0;  ba.om[1]=out_d0; ba.M[1]=M_d0; ba.nin[1]=n0; ba.nout[1]=n1; ba.toff[1]=t_d0;
  ba.im[2]=in_c1;  ba.om[2]=out_c1; ba.M[2]=M_c1; ba.nin[2]=n1; ba.nout[2]=n1; ba.toff[2]=t_c1;
  ba.im[3]=in_d1;  ba.om[3]=out_d1; ba.M[3]=M_d1; ba.nin[3]=n1; ba.nout[3]=n2; ba.toff[3]=t_d1;
  ba.im[4]=in_c2;  ba.om[4]=out_c2; ba.M[4]=M_c2; ba.nin[4]=n2; ba.nout[4]=n2; ba.toff[4]=t_c2;
  ba.im[5]=in_d2;  ba.om[5]=out_d2; ba.M[5]=M_d2; ba.nin[5]=n2; ba.nout[5]=n3; ba.toff[5]=t_d2;
  long maxM = M_c0;
  for (int i = 0; i < 6; ++i) if (ba.M[i] > maxM) maxM = ba.M[i];
  dim3 bg((unsigned)cdivl(maxM,256), 9, 6);
  build_all_kernel<<<bg,256,0,stream>>>(ba, tb);

  // 3) c0: feats fp32 -> fbuf(x) bf16 [n0][64]
  c0_tab_kernel<<<cdivl(n0,256),256,0,stream>>>(feats, w_c0, b_c0, tb + t_c0, fbuf, n0);

  // 4) d0: x bf16 -> out0 fp32 + bf0 bf16, relu
  mconv2_kernel<64,2,true><<<cdivl(n1,128),512,0,stream>>>(
      wsb, 0L, wtb_off, zp_off, b_d0, tb + t_d0, out0, bf0, n1);

  // 5) c1: bf0 bf16 -> fbuf(y) bf16
  mconv2_kernel<128,1,false><<<cdivl(n1,128),512,0,stream>>>(
      wsb, bf0_off, wtb_off + wt64*2, zp_off, b_c1, tb + t_c1, nullptr, fbuf, n1);

  // 6) d1: y bf16 -> out1 fp32 + bf1 bf16, relu
  mconv2_kernel<128,2,true><<<cdivl(n2,128),512,0,stream>>>(
      wsb, 0L, wtb_off + (wt64 + wt128)*2, zp_off, b_d1, tb + t_d1, out1, bf1, n2);

  // 7) c2: bf1 bf16 -> fbuf(z) bf16
  mconv2_kernel<128,1,false><<<cdivl(n2,128),512,0,stream>>>(
      wsb, bf1_off, wtb_off + (wt64 + 2*wt128)*2, zp_off, b_c2, tb + t_c2, nullptr, fbuf, n2);

  // 8) d2: z bf16 -> out2 fp32
  mconv2_kernel<128,0,false><<<cdivl(n3,128),512,0,stream>>>(
      wsb, 0L, wtb_off + (wt64 + 3*wt128)*2, zp_off, b_d2, tb + t_d2, out2, nullptr, n3);
}